// Round 2
// baseline (1508.531 us; speedup 1.0000x reference)
//
#include <hip/hip_runtime.h>

typedef __bf16 bf16x8 __attribute__((ext_vector_type(8)));
typedef float  f32x4  __attribute__((ext_vector_type(4)));

#define NNODES   50000
#define DIN      256
#define HEADS    32
#define CDIM     16
#define NH       512          // HEADS*CDIM
#define ERAW     800000
#define ETOT     850000

__device__ __forceinline__ float b2f(unsigned short u) {
    return __uint_as_float(((unsigned)u) << 16);
}
__device__ __forceinline__ unsigned short f2b(float f) {
    unsigned v = __float_as_uint(f);
    v += 0x7fffu + ((v >> 16) & 1u);           // RNE
    return (unsigned short)(v >> 16);
}

// probe edge_index width: int64 -> odd int32 slots are high words == 0
__global__ void k_detect(const int* __restrict__ ei, int* __restrict__ flag) {
    if (threadIdx.x == 0 && blockIdx.x == 0) {
        int nz = 0;
        #pragma unroll
        for (int t = 0; t < 64; ++t) nz |= ei[2 * t + 1];
        flag[0] = (nz == 0) ? 1 : 0;           // 1 => int64
    }
}

__device__ __forceinline__ void get_sd(const int* __restrict__ ei, int e, int is64,
                                       int& s, int& d) {
    if (e >= ERAW) { s = d = e - ERAW; return; }
    if (is64) { s = ei[2 * e]; d = ei[2 * ERAW + 2 * e]; }
    else      { s = ei[e];     d = ei[ERAW + e]; }
}

// Wt[n][k] = bf16(W[k][n]);  W is [256,512] row-major fp32
__global__ void k_transpose_w(const float* __restrict__ W,
                              unsigned short* __restrict__ Wt) {
    int n = blockIdx.x;      // 0..511
    int k = threadIdx.x;     // 0..255
    Wt[n * DIN + k] = f2b(W[k * NH + n]);
}

// xp[m][n] = sum_k x[m][k]*W[k][n]; x fp32 -> bf16 in-kernel, MFMA bf16, xp bf16.
// wave -> 16(M) x 64(N) tile. 3125 M-tiles * 8 N-groups = 25000 waves.
__global__ void k_gemm_xp(const float* __restrict__ x,
                          const unsigned short* __restrict__ Wt,
                          unsigned short* __restrict__ xp) {
    int wave = blockIdx.x * 4 + (threadIdx.x >> 6);
    int lane = threadIdx.x & 63;
    int mt = wave >> 3;          // 0..3124
    int ng = wave & 7;           // 0..7 (64 cols each)
    if (mt >= 3125) return;
    int r = lane & 15, quad = lane >> 4;

    const float* arow = x + (size_t)(mt * 16 + r) * DIN + quad * 8;
    f32x4 acc[4] = {};
    #pragma unroll
    for (int kc = 0; kc < 8; ++kc) {
        float4 a0 = *(const float4*)(arow + kc * 32);
        float4 a1 = *(const float4*)(arow + kc * 32 + 4);
        union { unsigned short u[8]; bf16x8 v; } ac;
        ac.u[0] = f2b(a0.x); ac.u[1] = f2b(a0.y); ac.u[2] = f2b(a0.z); ac.u[3] = f2b(a0.w);
        ac.u[4] = f2b(a1.x); ac.u[5] = f2b(a1.y); ac.u[6] = f2b(a1.z); ac.u[7] = f2b(a1.w);
        #pragma unroll
        for (int t = 0; t < 4; ++t) {
            int col = ng * 64 + t * 16 + r;
            bf16x8 b = *(const bf16x8*)(Wt + (size_t)col * DIN + kc * 32 + quad * 8);
            acc[t] = __builtin_amdgcn_mfma_f32_16x16x32_bf16(ac.v, b, acc[t], 0, 0, 0);
        }
    }
    #pragma unroll
    for (int t = 0; t < 4; ++t) {
        int col = ng * 64 + t * 16 + r;
        #pragma unroll
        for (int j = 0; j < 4; ++j) {
            int row = mt * 16 + quad * 4 + j;          // C/D: col=lane&15, row=quad*4+reg
            xp[(size_t)row * NH + col] = f2b(acc[t][j]);
        }
    }
}

// a_s[n,h] = sum_c xp[n,h,c]*att_src[h,c];  idx = n*32+h so xp offset = idx*16
__global__ void k_att(const unsigned short* __restrict__ xp,
                      const float* __restrict__ att_src,
                      const float* __restrict__ att_dst,
                      float* __restrict__ a_s, float* __restrict__ a_d) {
    int idx = blockIdx.x * 256 + threadIdx.x;          // exactly 1,600,000
    int h = idx & 31;
    const unsigned short* row = xp + (size_t)idx * CDIM;
    float s = 0.f, d = 0.f;
    #pragma unroll
    for (int c = 0; c < CDIM; ++c) {
        float v = b2f(row[c]);
        s += v * att_src[h * CDIM + c];
        d += v * att_dst[h * CDIM + c];
    }
    a_s[idx] = s;
    a_d[idx] = d;
}

__global__ void k_zero(float* __restrict__ p) {
    int idx = blockIdx.x * 256 + threadIdx.x;          // 2,400,000 (ssum+oacc)
    p[idx] = 0.f;
}

// denominator: ssum[dst,h] += exp(leaky(a_s[src,h]+a_d[dst,h]))
__global__ void k_edge_pass1(const int* __restrict__ ei, const int* __restrict__ flag,
                             const float* __restrict__ a_s,
                             const float* __restrict__ a_d,
                             float* __restrict__ ssum) {
    int idx = blockIdx.x * 256 + threadIdx.x;          // exactly 850000*32
    int e = idx >> 5, h = idx & 31;
    int s, d;
    get_sd(ei, e, flag[0], s, d);
    float v = a_s[s * HEADS + h] + a_d[d * HEADS + h];
    v = v > 0.f ? v : 0.2f * v;
    atomicAdd(&ssum[d * HEADS + h], __expf(v));
}

// out[dst,c] += sum_h alpha[e,h]*xp[src,h,c] ; wave per edge
__global__ void k_edge_pass2(const int* __restrict__ ei, const int* __restrict__ flag,
                             const unsigned short* __restrict__ xp,
                             const float* __restrict__ a_s,
                             const float* __restrict__ a_d,
                             const float* __restrict__ ssum,
                             float* __restrict__ oacc) {
    int e = blockIdx.x * 4 + (threadIdx.x >> 6);       // exactly 850000
    int lane = threadIdx.x & 63;
    int s, d;
    get_sd(ei, e, flag[0], s, d);
    int h = lane >> 1;
    float v = a_s[s * HEADS + h] + a_d[d * HEADS + h];
    v = v > 0.f ? v : 0.2f * v;
    float alpha = __expf(v) / (ssum[d * HEADS + h] + 1e-16f);

    // lane covers flat [h = lane>>1][c = (lane&1)*8 + j]
    const uint4 q = *(const uint4*)(xp + (size_t)s * NH + lane * 8);
    float f[8];
    f[0] = b2f((unsigned short)(q.x & 0xffff)) * alpha;
    f[1] = b2f((unsigned short)(q.x >> 16)) * alpha;
    f[2] = b2f((unsigned short)(q.y & 0xffff)) * alpha;
    f[3] = b2f((unsigned short)(q.y >> 16)) * alpha;
    f[4] = b2f((unsigned short)(q.z & 0xffff)) * alpha;
    f[5] = b2f((unsigned short)(q.z >> 16)) * alpha;
    f[6] = b2f((unsigned short)(q.w & 0xffff)) * alpha;
    f[7] = b2f((unsigned short)(q.w >> 16)) * alpha;

    #pragma unroll
    for (int m = 2; m <= 32; m <<= 1) {
        #pragma unroll
        for (int j = 0; j < 8; ++j) f[j] += __shfl_xor(f[j], m, 64);
    }
    if (lane < 2) {
        float* o = oacc + (size_t)d * CDIM + lane * 8;
        #pragma unroll
        for (int j = 0; j < 8; ++j) atomicAdd(&o[j], f[j]);
    }
}

__global__ void k_final(const float* __restrict__ oacc,
                        const float* __restrict__ bias,
                        float* __restrict__ out) {
    int idx = blockIdx.x * 256 + threadIdx.x;          // exactly 800000
    int c = idx & 15;
    float v = oacc[idx] * (1.0f / HEADS) + bias[c];
    out[idx] = v > 0.f ? v : expm1f(v);
}

// x_self = elu(elu(x@w1+b1)@w2+b2); one 64-thread block per node, fp32
__global__ void k_mlp(const float* __restrict__ x,
                      const float* __restrict__ w1,
                      const float* __restrict__ bb1,
                      const float* __restrict__ w2,
                      const float* __restrict__ bb2,
                      float* __restrict__ out) {
    __shared__ float xs[DIN];
    __shared__ float x1s[64];
    int n = blockIdx.x, t = threadIdx.x;
    float4 v = *(const float4*)(x + (size_t)n * DIN + t * 4);
    xs[t * 4 + 0] = v.x; xs[t * 4 + 1] = v.y;
    xs[t * 4 + 2] = v.z; xs[t * 4 + 3] = v.w;
    __syncthreads();
    float acc = bb1[t];
    #pragma unroll 4
    for (int k = 0; k < DIN; ++k) acc += xs[k] * w1[k * 64 + t];
    x1s[t] = acc > 0.f ? acc : expm1f(acc);
    __syncthreads();
    if (t < CDIM) {
        float a2 = bb2[t];
        #pragma unroll
        for (int k = 0; k < 64; ++k) a2 += x1s[k] * w2[k * CDIM + t];
        a2 = a2 > 0.f ? a2 : expm1f(a2);
        out[(size_t)n * CDIM + t] = a2;
    }
}

extern "C" void kernel_launch(void* const* d_in, const int* in_sizes, int n_in,
                              void* d_out, int out_size, void* d_ws, size_t ws_size,
                              hipStream_t stream) {
    const float* x  = (const float*)d_in[0];
    const int* ei   = (const int*)d_in[1];
    const float* W[2]    = {(const float*)d_in[2], (const float*)d_in[6]};
    const float* atS[2]  = {(const float*)d_in[3], (const float*)d_in[7]};
    const float* atD[2]  = {(const float*)d_in[4], (const float*)d_in[8]};
    const float* bias[2] = {(const float*)d_in[5], (const float*)d_in[9]};
    const float* w1 = (const float*)d_in[10];
    const float* b1 = (const float*)d_in[11];
    const float* w2 = (const float*)d_in[12];
    const float* b2 = (const float*)d_in[13];
    float* out = (float*)d_out;

    char* ws = (char*)d_ws;
    unsigned short* xp = (unsigned short*)(ws);               // 51,200,000 B
    unsigned short* Wt = (unsigned short*)(ws + 51200000);    //    262,144 B
    float* a_s  = (float*)(ws + 51462144);                    //  6,400,000 B
    float* a_d  = (float*)(ws + 57862144);                    //  6,400,000 B
    float* ssum = (float*)(ws + 64262144);                    //  6,400,000 B
    float* oacc = (float*)(ws + 70662144);                    //  3,200,000 B
    int*   flag = (int*)(ws + 73862144);                      //          4 B

    k_detect<<<1, 64, 0, stream>>>(ei, flag);
    for (int cv = 0; cv < 2; ++cv) {
        k_transpose_w<<<512, 256, 0, stream>>>(W[cv], Wt);
        k_gemm_xp   <<<6250, 256, 0, stream>>>(x, Wt, xp);
        k_att       <<<6250, 256, 0, stream>>>(xp, atS[cv], atD[cv], a_s, a_d);
        k_zero      <<<9375, 256, 0, stream>>>(ssum);         // ssum+oacc contiguous
        k_edge_pass1<<<106250, 256, 0, stream>>>(ei, flag, a_s, a_d, ssum);
        k_edge_pass2<<<212500, 256, 0, stream>>>(ei, flag, xp, a_s, a_d, ssum, oacc);
        k_final     <<<3125, 256, 0, stream>>>(oacc, bias[cv], out + (size_t)cv * 800000);
    }
    k_mlp<<<50000, 64, 0, stream>>>(x, w1, b1, w2, b2, out + 1600000);
}

// Round 3
// 1057.510 us; speedup vs baseline: 1.4265x; 1.4265x over previous
//
#include <hip/hip_runtime.h>

typedef __bf16 bf16x8 __attribute__((ext_vector_type(8)));
typedef float  f32x4  __attribute__((ext_vector_type(4)));

#define NNODES   50000
#define DIN      256
#define HEADS    32
#define CDIM     16
#define NH       512          // HEADS*CDIM
#define ERAW     800000
#define SCAN_B   196          // ceil(50000/256)

__device__ __forceinline__ float b2f(unsigned short u) {
    return __uint_as_float(((unsigned)u) << 16);
}
__device__ __forceinline__ unsigned short f2b(float f) {
    unsigned v = __float_as_uint(f);
    v += 0x7fffu + ((v >> 16) & 1u);           // RNE
    return (unsigned short)(v >> 16);
}

// probe edge_index width: int64 -> odd int32 slots are high words == 0
__global__ void k_detect(const int* __restrict__ ei, int* __restrict__ flag) {
    if (threadIdx.x == 0 && blockIdx.x == 0) {
        int nz = 0;
        #pragma unroll
        for (int t = 0; t < 64; ++t) nz |= ei[2 * t + 1];
        flag[0] = (nz == 0) ? 1 : 0;           // 1 => int64
    }
}

// ---------------- CSR build (dst-sorted), raw edges only ----------------
__global__ void k_zero_deg(int* __restrict__ deg) {
    int i = blockIdx.x * 256 + threadIdx.x;
    if (i < NNODES) deg[i] = 0;
}

__global__ void k_hist(const int* __restrict__ ei, const int* __restrict__ flag,
                       int* __restrict__ deg) {
    int e = blockIdx.x * 256 + threadIdx.x;    // exactly 800000
    int d = flag[0] ? ei[2 * ERAW + 2 * e] : ei[ERAW + e];
    atomicAdd(&deg[d], 1);
}

__global__ void k_scan_blk(const int* __restrict__ deg, int* __restrict__ part,
                           int* __restrict__ bsum) {
    __shared__ int sm[256];
    int b = blockIdx.x, t = threadIdx.x, i = b * 256 + t;
    int v = (i < NNODES) ? deg[i] : 0;
    sm[t] = v; __syncthreads();
    for (int off = 1; off < 256; off <<= 1) {
        int u = (t >= off) ? sm[t - off] : 0;
        __syncthreads();
        sm[t] += u; __syncthreads();
    }
    if (i < NNODES) part[i] = sm[t] - v;       // exclusive within block
    if (t == 255) bsum[b] = sm[255];
}

__global__ void k_scan_top(int* __restrict__ bsum) {
    __shared__ int sm[256];
    int t = threadIdx.x;
    int v = (t < SCAN_B) ? bsum[t] : 0;
    sm[t] = v; __syncthreads();
    for (int off = 1; off < 256; off <<= 1) {
        int u = (t >= off) ? sm[t - off] : 0;
        __syncthreads();
        sm[t] += u; __syncthreads();
    }
    if (t < SCAN_B) bsum[t] = sm[t] - v;       // exclusive block offsets
}

__global__ void k_scan_add(const int* __restrict__ part, const int* __restrict__ bsum,
                           int* __restrict__ rs, int* __restrict__ cur) {
    int b = blockIdx.x, t = threadIdx.x, i = b * 256 + t;
    if (i < NNODES) { int r = part[i] + bsum[b]; rs[i] = r; cur[i] = r; }
}

__global__ void k_scatter(const int* __restrict__ ei, const int* __restrict__ flag,
                          int* __restrict__ cur, int* __restrict__ csr) {
    int e = blockIdx.x * 256 + threadIdx.x;    // exactly 800000
    int s, d;
    if (flag[0]) { s = ei[2 * e]; d = ei[2 * ERAW + 2 * e]; }
    else         { s = ei[e];     d = ei[ERAW + e]; }
    int pos = atomicAdd(&cur[d], 1);
    csr[pos] = s;
}

// ---------------- dense compute ----------------
// Wt[n][k] = bf16(W[k][n]);  W is [256,512] row-major fp32
__global__ void k_transpose_w(const float* __restrict__ W,
                              unsigned short* __restrict__ Wt) {
    int n = blockIdx.x;      // 0..511
    int k = threadIdx.x;     // 0..255
    Wt[n * DIN + k] = f2b(W[k * NH + n]);
}

// xp[m][n] = sum_k x[m][k]*W[k][n]; x fp32 -> bf16 in-kernel, MFMA bf16, xp bf16.
__global__ void k_gemm_xp(const float* __restrict__ x,
                          const unsigned short* __restrict__ Wt,
                          unsigned short* __restrict__ xp) {
    int wave = blockIdx.x * 4 + (threadIdx.x >> 6);
    int lane = threadIdx.x & 63;
    int mt = wave >> 3;          // 0..3124
    int ng = wave & 7;           // 0..7 (64 cols each)
    if (mt >= 3125) return;
    int r = lane & 15, quad = lane >> 4;

    const float* arow = x + (size_t)(mt * 16 + r) * DIN + quad * 8;
    f32x4 acc[4] = {};
    #pragma unroll
    for (int kc = 0; kc < 8; ++kc) {
        float4 a0 = *(const float4*)(arow + kc * 32);
        float4 a1 = *(const float4*)(arow + kc * 32 + 4);
        union { unsigned short u[8]; bf16x8 v; } ac;
        ac.u[0] = f2b(a0.x); ac.u[1] = f2b(a0.y); ac.u[2] = f2b(a0.z); ac.u[3] = f2b(a0.w);
        ac.u[4] = f2b(a1.x); ac.u[5] = f2b(a1.y); ac.u[6] = f2b(a1.z); ac.u[7] = f2b(a1.w);
        #pragma unroll
        for (int t = 0; t < 4; ++t) {
            int col = ng * 64 + t * 16 + r;
            bf16x8 b = *(const bf16x8*)(Wt + (size_t)col * DIN + kc * 32 + quad * 8);
            acc[t] = __builtin_amdgcn_mfma_f32_16x16x32_bf16(ac.v, b, acc[t], 0, 0, 0);
        }
    }
    #pragma unroll
    for (int t = 0; t < 4; ++t) {
        int col = ng * 64 + t * 16 + r;
        #pragma unroll
        for (int j = 0; j < 4; ++j) {
            int row = mt * 16 + quad * 4 + j;          // C/D: col=lane&15, row=quad*4+reg
            xp[(size_t)row * NH + col] = f2b(acc[t][j]);
        }
    }
}

// a_s[n,h] = sum_c xp[n,h,c]*att_src[h,c]
__global__ void k_att(const unsigned short* __restrict__ xp,
                      const float* __restrict__ att_src,
                      const float* __restrict__ att_dst,
                      float* __restrict__ a_s, float* __restrict__ a_d) {
    int idx = blockIdx.x * 256 + threadIdx.x;          // exactly 1,600,000
    int h = idx & 31;
    const unsigned short* row = xp + (size_t)idx * CDIM;
    float s = 0.f, d = 0.f;
    #pragma unroll
    for (int c = 0; c < CDIM; ++c) {
        float v = b2f(row[c]);
        s += v * att_src[h * CDIM + c];
        d += v * att_dst[h * CDIM + c];
    }
    a_s[idx] = s;
    a_d[idx] = d;
}

// One wave per dst node: inline softmax denom + weighted gather, no atomics.
// lane covers flat (h = lane>>1, c = (lane&1)*8 + j)
__global__ void k_conv(const int* __restrict__ csr, const int* __restrict__ rs,
                       const int* __restrict__ deg,
                       const unsigned short* __restrict__ xp,
                       const float* __restrict__ a_s, const float* __restrict__ a_d,
                       const float* __restrict__ bias, float* __restrict__ out) {
    int w = blockIdx.x * 4 + (threadIdx.x >> 6);       // exactly 50000
    int lane = threadIdx.x & 63;
    int h2 = lane >> 1;
    float adn = a_d[w * HEADS + h2];
    int beg = rs[w], cnt = deg[w];

    // denominator: self-loop + in-edges
    float v0 = a_s[w * HEADS + h2] + adn;
    v0 = v0 > 0.f ? v0 : 0.2f * v0;
    float denom = __expf(v0);
    for (int i = 0; i < cnt; ++i) {
        int s = csr[beg + i];
        float t = a_s[s * HEADS + h2] + adn;
        t = t > 0.f ? t : 0.2f * t;
        denom += __expf(t);
    }
    float inv = 1.f / (denom + 1e-16f);

    float acc[8] = {0, 0, 0, 0, 0, 0, 0, 0};
    {   // self contribution
        float al = __expf(v0) * inv;
        const uint4 q = *(const uint4*)(xp + (size_t)w * NH + lane * 8);
        unsigned u[4] = {q.x, q.y, q.z, q.w};
        #pragma unroll
        for (int j = 0; j < 4; ++j) {
            acc[2 * j]     += b2f((unsigned short)(u[j] & 0xffff)) * al;
            acc[2 * j + 1] += b2f((unsigned short)(u[j] >> 16)) * al;
        }
    }
    for (int i = 0; i < cnt; ++i) {
        int s = csr[beg + i];
        float t = a_s[s * HEADS + h2] + adn;           // L1/L2-hot: read in loop 1
        t = t > 0.f ? t : 0.2f * t;
        float al = __expf(t) * inv;
        const uint4 q = *(const uint4*)(xp + (size_t)s * NH + lane * 8);
        unsigned u[4] = {q.x, q.y, q.z, q.w};
        #pragma unroll
        for (int j = 0; j < 4; ++j) {
            acc[2 * j]     += b2f((unsigned short)(u[j] & 0xffff)) * al;
            acc[2 * j + 1] += b2f((unsigned short)(u[j] >> 16)) * al;
        }
    }

    #pragma unroll
    for (int m = 2; m <= 32; m <<= 1) {
        #pragma unroll
        for (int j = 0; j < 8; ++j) acc[j] += __shfl_xor(acc[j], m, 64);
    }
    if (lane < 2) {                                    // lane0: c=0..7, lane1: c=8..15
        #pragma unroll
        for (int j = 0; j < 8; ++j) {
            int c = lane * 8 + j;
            float o = acc[j] * (1.0f / HEADS) + bias[c];
            out[(size_t)w * CDIM + c] = o > 0.f ? o : expm1f(o);
        }
    }
}

// x_self = elu(elu(x@w1+b1)@w2+b2); one 64-thread block per node, fp32
__global__ void k_mlp(const float* __restrict__ x,
                      const float* __restrict__ w1,
                      const float* __restrict__ bb1,
                      const float* __restrict__ w2,
                      const float* __restrict__ bb2,
                      float* __restrict__ out) {
    __shared__ float xs[DIN];
    __shared__ float x1s[64];
    int n = blockIdx.x, t = threadIdx.x;
    float4 v = *(const float4*)(x + (size_t)n * DIN + t * 4);
    xs[t * 4 + 0] = v.x; xs[t * 4 + 1] = v.y;
    xs[t * 4 + 2] = v.z; xs[t * 4 + 3] = v.w;
    __syncthreads();
    float acc = bb1[t];
    #pragma unroll 4
    for (int k = 0; k < DIN; ++k) acc += xs[k] * w1[k * 64 + t];
    x1s[t] = acc > 0.f ? acc : expm1f(acc);
    __syncthreads();
    if (t < CDIM) {
        float a2 = bb2[t];
        #pragma unroll
        for (int k = 0; k < 64; ++k) a2 += x1s[k] * w2[k * CDIM + t];
        a2 = a2 > 0.f ? a2 : expm1f(a2);
        out[(size_t)n * CDIM + t] = a2;
    }
}

extern "C" void kernel_launch(void* const* d_in, const int* in_sizes, int n_in,
                              void* d_out, int out_size, void* d_ws, size_t ws_size,
                              hipStream_t stream) {
    const float* x  = (const float*)d_in[0];
    const int* ei   = (const int*)d_in[1];
    const float* W[2]    = {(const float*)d_in[2], (const float*)d_in[6]};
    const float* atS[2]  = {(const float*)d_in[3], (const float*)d_in[7]};
    const float* atD[2]  = {(const float*)d_in[4], (const float*)d_in[8]};
    const float* bias[2] = {(const float*)d_in[5], (const float*)d_in[9]};
    const float* w1 = (const float*)d_in[10];
    const float* b1 = (const float*)d_in[11];
    const float* w2 = (const float*)d_in[12];
    const float* b2 = (const float*)d_in[13];
    float* out = (float*)d_out;

    char* ws = (char*)d_ws;
    unsigned short* xp = (unsigned short*)(ws);               // 51,200,000 B
    unsigned short* Wt = (unsigned short*)(ws + 51200000);    //    262,144 B
    float* a_s = (float*)(ws + 51462144);                     //  6,400,000 B
    float* a_d = (float*)(ws + 57862144);                     //  6,400,000 B
    int* deg   = (int*)(ws + 64262144);                       //    200,000 B
    int* rs    = (int*)(ws + 64462144);                       //    200,000 B
    int* cur   = (int*)(ws + 64662144);                       //    200,000 B
    int* part  = (int*)(ws + 64862144);                       //    200,000 B
    int* bsum  = (int*)(ws + 65062144);                       //      1,024 B
    int* csr   = (int*)(ws + 65063168);                       //  3,200,000 B
    int* flag  = (int*)(ws + 68263168);                       //          4 B

    k_detect<<<1, 64, 0, stream>>>(ei, flag);
    // CSR build (once; shared by both convs)
    k_zero_deg<<<SCAN_B, 256, 0, stream>>>(deg);
    k_hist    <<<3125, 256, 0, stream>>>(ei, flag, deg);
    k_scan_blk<<<SCAN_B, 256, 0, stream>>>(deg, part, bsum);
    k_scan_top<<<1, 256, 0, stream>>>(bsum);
    k_scan_add<<<SCAN_B, 256, 0, stream>>>(part, bsum, rs, cur);
    k_scatter <<<3125, 256, 0, stream>>>(ei, flag, cur, csr);

    for (int cv = 0; cv < 2; ++cv) {
        k_transpose_w<<<512, 256, 0, stream>>>(W[cv], Wt);
        k_gemm_xp   <<<6250, 256, 0, stream>>>(x, Wt, xp);
        k_att       <<<6250, 256, 0, stream>>>(xp, atS[cv], atD[cv], a_s, a_d);
        k_conv      <<<12500, 256, 0, stream>>>(csr, rs, deg, xp, a_s, a_d,
                                                bias[cv], out + (size_t)cv * 800000);
    }
    k_mlp<<<50000, 64, 0, stream>>>(x, w1, b1, w2, b2, out + 1600000);
}

// Round 4
// 695.204 us; speedup vs baseline: 2.1699x; 1.5212x over previous
//
#include <hip/hip_runtime.h>

typedef __bf16 bf16x8 __attribute__((ext_vector_type(8)));
typedef float  f32x4  __attribute__((ext_vector_type(4)));

#define NNODES   50000
#define DIN      256
#define HEADS    32
#define CDIM     16
#define NH       512          // HEADS*CDIM
#define ERAW     800000
#define SCAN_B   196          // ceil(50000/256)

__device__ __forceinline__ float b2f(unsigned short u) {
    return __uint_as_float(((unsigned)u) << 16);
}
__device__ __forceinline__ unsigned short f2b(float f) {
    unsigned v = __float_as_uint(f);
    v += 0x7fffu + ((v >> 16) & 1u);           // RNE
    return (unsigned short)(v >> 16);
}

// probe edge_index width: int64 -> odd int32 slots are high words == 0
__global__ void k_detect(const int* __restrict__ ei, int* __restrict__ flag) {
    if (threadIdx.x == 0 && blockIdx.x == 0) {
        int nz = 0;
        #pragma unroll
        for (int t = 0; t < 64; ++t) nz |= ei[2 * t + 1];
        flag[0] = (nz == 0) ? 1 : 0;           // 1 => int64
    }
}

// ---------------- CSR build (dst-sorted), raw edges only ----------------
__global__ void k_zero_deg(int* __restrict__ deg) {
    int i = blockIdx.x * 256 + threadIdx.x;
    if (i < NNODES) deg[i] = 0;
}

__global__ void k_hist(const int* __restrict__ ei, const int* __restrict__ flag,
                       int* __restrict__ deg) {
    int e = blockIdx.x * 256 + threadIdx.x;    // exactly 800000
    int d = flag[0] ? ei[2 * ERAW + 2 * e] : ei[ERAW + e];
    atomicAdd(&deg[d], 1);
}

__global__ void k_scan_blk(const int* __restrict__ deg, int* __restrict__ part,
                           int* __restrict__ bsum) {
    __shared__ int sm[256];
    int b = blockIdx.x, t = threadIdx.x, i = b * 256 + t;
    int v = (i < NNODES) ? deg[i] : 0;
    sm[t] = v; __syncthreads();
    for (int off = 1; off < 256; off <<= 1) {
        int u = (t >= off) ? sm[t - off] : 0;
        __syncthreads();
        sm[t] += u; __syncthreads();
    }
    if (i < NNODES) part[i] = sm[t] - v;
    if (t == 255) bsum[b] = sm[255];
}

__global__ void k_scan_top(int* __restrict__ bsum) {
    __shared__ int sm[256];
    int t = threadIdx.x;
    int v = (t < SCAN_B) ? bsum[t] : 0;
    sm[t] = v; __syncthreads();
    for (int off = 1; off < 256; off <<= 1) {
        int u = (t >= off) ? sm[t - off] : 0;
        __syncthreads();
        sm[t] += u; __syncthreads();
    }
    if (t < SCAN_B) bsum[t] = sm[t] - v;
}

__global__ void k_scan_add(const int* __restrict__ part, const int* __restrict__ bsum,
                           int* __restrict__ rs, int* __restrict__ cur) {
    int b = blockIdx.x, t = threadIdx.x, i = b * 256 + t;
    if (i < NNODES) { int r = part[i] + bsum[b]; rs[i] = r; cur[i] = r; }
}

__global__ void k_scatter(const int* __restrict__ ei, const int* __restrict__ flag,
                          int* __restrict__ cur, int* __restrict__ csr) {
    int e = blockIdx.x * 256 + threadIdx.x;    // exactly 800000
    int s, d;
    if (flag[0]) { s = ei[2 * e]; d = ei[2 * ERAW + 2 * e]; }
    else         { s = ei[e];     d = ei[ERAW + e]; }
    int pos = atomicAdd(&cur[d], 1);
    csr[pos] = s;
}

// ---------------- dense compute ----------------
// dst[n*K+k] = bf16(src[k*N+n]); grid: N blocks, K threads
__global__ void k_tr(const float* __restrict__ src, unsigned short* __restrict__ dst,
                     int K, int N) {
    int n = blockIdx.x, k = threadIdx.x;
    dst[n * K + k] = f2b(src[k * N + n]);
}

// xp = x @ W  (bf16 MFMA). Block: 64 rows x 256 cols (4 waves, wave = 64x64).
__global__ void k_gemm_xp(const float* __restrict__ x,
                          const unsigned short* __restrict__ Wt,
                          unsigned short* __restrict__ xp) {
    int bid = blockIdx.x;
    int mt4 = bid >> 1, nh = bid & 1;
    int w = threadIdx.x >> 6, lane = threadIdx.x & 63;
    int ng = nh * 4 + w;
    int r = lane & 15, quad = lane >> 4;
    int row0 = mt4 * 64;

    f32x4 acc[4][4] = {};
    #pragma unroll
    for (int kc = 0; kc < 8; ++kc) {
        bf16x8 a[4];
        #pragma unroll
        for (int sub = 0; sub < 4; ++sub) {
            union { unsigned short u[8]; bf16x8 v; } ac;
            if (row0 + sub * 16 < NNODES) {            // wave-uniform guard
                const float* p = x + (size_t)(row0 + sub * 16 + r) * DIN + kc * 32 + quad * 8;
                float4 a0 = *(const float4*)p;
                float4 a1 = *(const float4*)(p + 4);
                ac.u[0] = f2b(a0.x); ac.u[1] = f2b(a0.y); ac.u[2] = f2b(a0.z); ac.u[3] = f2b(a0.w);
                ac.u[4] = f2b(a1.x); ac.u[5] = f2b(a1.y); ac.u[6] = f2b(a1.z); ac.u[7] = f2b(a1.w);
            } else {
                #pragma unroll
                for (int j = 0; j < 8; ++j) ac.u[j] = 0;
            }
            a[sub] = ac.v;
        }
        #pragma unroll
        for (int t = 0; t < 4; ++t) {
            int col = ng * 64 + t * 16 + r;
            bf16x8 b = *(const bf16x8*)(Wt + (size_t)col * DIN + kc * 32 + quad * 8);
            #pragma unroll
            for (int sub = 0; sub < 4; ++sub)
                acc[sub][t] = __builtin_amdgcn_mfma_f32_16x16x32_bf16(a[sub], b, acc[sub][t], 0, 0, 0);
        }
    }
    #pragma unroll
    for (int sub = 0; sub < 4; ++sub) {
        if (row0 + sub * 16 >= NNODES) continue;
        #pragma unroll
        for (int t = 0; t < 4; ++t) {
            int col = ng * 64 + t * 16 + r;
            #pragma unroll
            for (int j = 0; j < 4; ++j) {
                int row = row0 + sub * 16 + quad * 4 + j;
                xp[(size_t)row * NH + col] = f2b(acc[sub][t][j]);
            }
        }
    }
}

// a_s[n,h] = sum_c xp[n,h,c]*att_src[h,c]
__global__ void k_att(const unsigned short* __restrict__ xp,
                      const float* __restrict__ att_src,
                      const float* __restrict__ att_dst,
                      float* __restrict__ a_s, float* __restrict__ a_d) {
    int idx = blockIdx.x * 256 + threadIdx.x;          // exactly 1,600,000
    int h = idx & 31;
    const unsigned short* row = xp + (size_t)idx * CDIM;
    float s = 0.f, d = 0.f;
    #pragma unroll
    for (int c = 0; c < CDIM; ++c) {
        float v = b2f(row[c]);
        s += v * att_src[h * CDIM + c];
        d += v * att_dst[h * CDIM + c];
    }
    a_s[idx] = s;
    a_d[idx] = d;
}

// One wave per dst node; single merged pass (unnormalized accumulate + denom).
__global__ void k_conv(const int* __restrict__ csr, const int* __restrict__ rs,
                       const int* __restrict__ deg,
                       const unsigned short* __restrict__ xp,
                       const float* __restrict__ a_s, const float* __restrict__ a_d,
                       const float* __restrict__ bias, float* __restrict__ out) {
    int w = blockIdx.x * 4 + (threadIdx.x >> 6);       // exactly 50000
    int lane = threadIdx.x & 63;
    int h2 = lane >> 1;
    float adn = a_d[w * HEADS + h2];
    int beg = __builtin_amdgcn_readfirstlane(rs[w]);
    int cnt = __builtin_amdgcn_readfirstlane(deg[w]);

    float denom = 0.f;
    float acc[8] = {0, 0, 0, 0, 0, 0, 0, 0};

    {   // self contribution
        float t = a_s[w * HEADS + h2] + adn;
        t = t > 0.f ? t : 0.2f * t;
        float e = __expf(t);
        denom += e;
        const uint4 q = *(const uint4*)(xp + (size_t)w * NH + lane * 8);
        unsigned u[4] = {q.x, q.y, q.z, q.w};
        #pragma unroll
        for (int j = 0; j < 4; ++j) {
            acc[2 * j]     += e * b2f((unsigned short)(u[j] & 0xffff));
            acc[2 * j + 1] += e * b2f((unsigned short)(u[j] >> 16));
        }
    }

    int i = 0;
    for (; i + 4 <= cnt; i += 4) {
        int s0 = csr[beg + i],     s1 = csr[beg + i + 1];
        int s2 = csr[beg + i + 2], s3 = csr[beg + i + 3];
        float av[4];
        av[0] = a_s[s0 * HEADS + h2]; av[1] = a_s[s1 * HEADS + h2];
        av[2] = a_s[s2 * HEADS + h2]; av[3] = a_s[s3 * HEADS + h2];
        uint4 qv[4];
        qv[0] = *(const uint4*)(xp + (size_t)s0 * NH + lane * 8);
        qv[1] = *(const uint4*)(xp + (size_t)s1 * NH + lane * 8);
        qv[2] = *(const uint4*)(xp + (size_t)s2 * NH + lane * 8);
        qv[3] = *(const uint4*)(xp + (size_t)s3 * NH + lane * 8);
        #pragma unroll
        for (int k = 0; k < 4; ++k) {
            float t = av[k] + adn;
            t = t > 0.f ? t : 0.2f * t;
            float e = __expf(t);
            denom += e;
            unsigned u[4] = {qv[k].x, qv[k].y, qv[k].z, qv[k].w};
            #pragma unroll
            for (int j = 0; j < 4; ++j) {
                acc[2 * j]     += e * b2f((unsigned short)(u[j] & 0xffff));
                acc[2 * j + 1] += e * b2f((unsigned short)(u[j] >> 16));
            }
        }
    }
    for (; i < cnt; ++i) {
        int s = csr[beg + i];
        float t = a_s[s * HEADS + h2] + adn;
        t = t > 0.f ? t : 0.2f * t;
        float e = __expf(t);
        denom += e;
        const uint4 q = *(const uint4*)(xp + (size_t)s * NH + lane * 8);
        unsigned u[4] = {q.x, q.y, q.z, q.w};
        #pragma unroll
        for (int j = 0; j < 4; ++j) {
            acc[2 * j]     += e * b2f((unsigned short)(u[j] & 0xffff));
            acc[2 * j + 1] += e * b2f((unsigned short)(u[j] >> 16));
        }
    }

    float inv = 1.f / (denom + 1e-16f);
    #pragma unroll
    for (int j = 0; j < 8; ++j) acc[j] *= inv;

    #pragma unroll
    for (int m = 2; m <= 32; m <<= 1) {
        #pragma unroll
        for (int j = 0; j < 8; ++j) acc[j] += __shfl_xor(acc[j], m, 64);
    }
    if (lane < 2) {
        #pragma unroll
        for (int j = 0; j < 8; ++j) {
            int c = lane * 8 + j;
            float o = acc[j] * (1.0f / HEADS) + bias[c];
            out[(size_t)w * CDIM + c] = o > 0.f ? o : expm1f(o);
        }
    }
}

// x1 = elu(x @ w1t + b1); wave = 64 rows x 64 cols; 782 active waves
__global__ void k_mlp1(const float* __restrict__ x, const unsigned short* __restrict__ w1t,
                       const float* __restrict__ bb1, unsigned short* __restrict__ x1) {
    int wave = blockIdx.x * 4 + (threadIdx.x >> 6);
    if (wave >= 782) return;
    int lane = threadIdx.x & 63;
    int r = lane & 15, quad = lane >> 4;
    int row0 = wave * 64;

    f32x4 acc[4][4] = {};
    #pragma unroll
    for (int kc = 0; kc < 8; ++kc) {
        bf16x8 a[4];
        #pragma unroll
        for (int sub = 0; sub < 4; ++sub) {
            union { unsigned short u[8]; bf16x8 v; } ac;
            if (row0 + sub * 16 < NNODES) {
                const float* p = x + (size_t)(row0 + sub * 16 + r) * DIN + kc * 32 + quad * 8;
                float4 a0 = *(const float4*)p;
                float4 a1 = *(const float4*)(p + 4);
                ac.u[0] = f2b(a0.x); ac.u[1] = f2b(a0.y); ac.u[2] = f2b(a0.z); ac.u[3] = f2b(a0.w);
                ac.u[4] = f2b(a1.x); ac.u[5] = f2b(a1.y); ac.u[6] = f2b(a1.z); ac.u[7] = f2b(a1.w);
            } else {
                #pragma unroll
                for (int j = 0; j < 8; ++j) ac.u[j] = 0;
            }
            a[sub] = ac.v;
        }
        #pragma unroll
        for (int t = 0; t < 4; ++t) {
            int col = t * 16 + r;
            bf16x8 b = *(const bf16x8*)(w1t + (size_t)col * DIN + kc * 32 + quad * 8);
            #pragma unroll
            for (int sub = 0; sub < 4; ++sub)
                acc[sub][t] = __builtin_amdgcn_mfma_f32_16x16x32_bf16(a[sub], b, acc[sub][t], 0, 0, 0);
        }
    }
    #pragma unroll
    for (int sub = 0; sub < 4; ++sub) {
        if (row0 + sub * 16 >= NNODES) continue;
        #pragma unroll
        for (int t = 0; t < 4; ++t) {
            int col = t * 16 + r;
            float bv = bb1[col];
            #pragma unroll
            for (int j = 0; j < 4; ++j) {
                int row = row0 + sub * 16 + quad * 4 + j;
                float v = acc[sub][t][j] + bv;
                v = v > 0.f ? v : expm1f(v);
                x1[(size_t)row * 64 + col] = f2b(v);
            }
        }
    }
}

// out = elu(x1 @ w2t + b2); wave = 16 rows x 16 cols; 3125 active waves
__global__ void k_mlp2(const unsigned short* __restrict__ x1,
                       const unsigned short* __restrict__ w2t,
                       const float* __restrict__ bb2, float* __restrict__ out) {
    int wave = blockIdx.x * 4 + (threadIdx.x >> 6);
    if (wave >= 3125) return;
    int lane = threadIdx.x & 63;
    int r = lane & 15, quad = lane >> 4;

    f32x4 acc = {};
    #pragma unroll
    for (int kc = 0; kc < 2; ++kc) {
        bf16x8 a = *(const bf16x8*)(x1 + (size_t)(wave * 16 + r) * 64 + kc * 32 + quad * 8);
        bf16x8 b = *(const bf16x8*)(w2t + (size_t)r * 64 + kc * 32 + quad * 8);
        acc = __builtin_amdgcn_mfma_f32_16x16x32_bf16(a, b, acc, 0, 0, 0);
    }
    float bv = bb2[r];
    #pragma unroll
    for (int j = 0; j < 4; ++j) {
        int row = wave * 16 + quad * 4 + j;
        float v = acc[j] + bv;
        v = v > 0.f ? v : expm1f(v);
        out[(size_t)row * CDIM + r] = v;
    }
}

extern "C" void kernel_launch(void* const* d_in, const int* in_sizes, int n_in,
                              void* d_out, int out_size, void* d_ws, size_t ws_size,
                              hipStream_t stream) {
    const float* x  = (const float*)d_in[0];
    const int* ei   = (const int*)d_in[1];
    const float* W[2]    = {(const float*)d_in[2], (const float*)d_in[6]};
    const float* atS[2]  = {(const float*)d_in[3], (const float*)d_in[7]};
    const float* atD[2]  = {(const float*)d_in[4], (const float*)d_in[8]};
    const float* bias[2] = {(const float*)d_in[5], (const float*)d_in[9]};
    const float* w1 = (const float*)d_in[10];
    const float* b1 = (const float*)d_in[11];
    const float* w2 = (const float*)d_in[12];
    const float* b2 = (const float*)d_in[13];
    float* out = (float*)d_out;

    char* ws = (char*)d_ws;
    unsigned short* xp  = (unsigned short*)(ws);              // 51,200,000 B
    unsigned short* Wt  = (unsigned short*)(ws + 51200000);   //    262,144 B
    unsigned short* w1t = (unsigned short*)(ws + 51462144);   //     32,768 B
    unsigned short* w2t = (unsigned short*)(ws + 51494912);   //      2,048 B
    unsigned short* x1  = (unsigned short*)(ws + 51496960);   //  6,400,000 B
    float* a_s = (float*)(ws + 57896960);                     //  6,400,000 B
    float* a_d = (float*)(ws + 64296960);                     //  6,400,000 B
    int* deg   = (int*)(ws + 70696960);                       //    200,000 B
    int* rs    = (int*)(ws + 70896960);                       //    200,000 B
    int* cur   = (int*)(ws + 71096960);                       //    200,000 B
    int* part  = (int*)(ws + 71296960);                       //    200,000 B
    int* bsum  = (int*)(ws + 71496960);                       //      1,024 B
    int* csr   = (int*)(ws + 71497984);                       //  3,200,000 B
    int* flag  = (int*)(ws + 74697984);                       //          4 B

    k_detect<<<1, 64, 0, stream>>>(ei, flag);
    k_zero_deg<<<SCAN_B, 256, 0, stream>>>(deg);
    k_hist    <<<3125, 256, 0, stream>>>(ei, flag, deg);
    k_scan_blk<<<SCAN_B, 256, 0, stream>>>(deg, part, bsum);
    k_scan_top<<<1, 256, 0, stream>>>(bsum);
    k_scan_add<<<SCAN_B, 256, 0, stream>>>(part, bsum, rs, cur);
    k_scatter <<<3125, 256, 0, stream>>>(ei, flag, cur, csr);

    k_tr<<<64, 256, 0, stream>>>(w1, w1t, DIN, 64);
    k_tr<<<16, 64, 0, stream>>>(w2, w2t, 64, CDIM);

    for (int cv = 0; cv < 2; ++cv) {
        k_tr     <<<512, 256, 0, stream>>>(W[cv], Wt, DIN, NH);
        k_gemm_xp<<<1564, 256, 0, stream>>>(x, Wt, xp);
        k_att    <<<6250, 256, 0, stream>>>(xp, atS[cv], atD[cv], a_s, a_d);
        k_conv   <<<12500, 256, 0, stream>>>(csr, rs, deg, xp, a_s, a_d,
                                             bias[cv], out + (size_t)cv * 800000);
    }
    k_mlp1<<<196, 256, 0, stream>>>(x, w1t, b1, x1);
    k_mlp2<<<782, 256, 0, stream>>>(x1, w2t, b2, out + 1600000);
}

// Round 5
// 688.133 us; speedup vs baseline: 2.1922x; 1.0103x over previous
//
#include <hip/hip_runtime.h>

typedef __bf16 bf16x8 __attribute__((ext_vector_type(8)));
typedef float  f32x4  __attribute__((ext_vector_type(4)));

#define NNODES   50000
#define DIN      256
#define HEADS    32
#define CDIM     16
#define NH       512          // HEADS*CDIM
#define ERAW     800000
#define SCAN_B   196          // ceil(50000/256)
#define LDSP     264          // 256 + 8 pad: r-stride 132 dwords -> 2-way bank alias (free)

__device__ __forceinline__ float b2f(unsigned short u) {
    return __uint_as_float(((unsigned)u) << 16);
}
__device__ __forceinline__ unsigned short f2b(float f) {
    unsigned v = __float_as_uint(f);
    v += 0x7fffu + ((v >> 16) & 1u);           // RNE
    return (unsigned short)(v >> 16);
}

// probe edge_index width: int64 -> odd int32 slots are high words == 0
__global__ void k_detect(const int* __restrict__ ei, int* __restrict__ flag) {
    if (threadIdx.x == 0 && blockIdx.x == 0) {
        int nz = 0;
        #pragma unroll
        for (int t = 0; t < 64; ++t) nz |= ei[2 * t + 1];
        flag[0] = (nz == 0) ? 1 : 0;           // 1 => int64
    }
}

// ---------------- CSR build (dst-sorted), raw edges only ----------------
__global__ void k_zero_deg(int* __restrict__ deg) {
    int i = blockIdx.x * 256 + threadIdx.x;
    if (i < NNODES) deg[i] = 0;
}

__global__ void k_hist(const int* __restrict__ ei, const int* __restrict__ flag,
                       int* __restrict__ deg) {
    int e = blockIdx.x * 256 + threadIdx.x;    // exactly 800000
    int d = flag[0] ? ei[2 * ERAW + 2 * e] : ei[ERAW + e];
    atomicAdd(&deg[d], 1);
}

__global__ void k_scan_blk(const int* __restrict__ deg, int* __restrict__ part,
                           int* __restrict__ bsum) {
    __shared__ int sm[256];
    int b = blockIdx.x, t = threadIdx.x, i = b * 256 + t;
    int v = (i < NNODES) ? deg[i] : 0;
    sm[t] = v; __syncthreads();
    for (int off = 1; off < 256; off <<= 1) {
        int u = (t >= off) ? sm[t - off] : 0;
        __syncthreads();
        sm[t] += u; __syncthreads();
    }
    if (i < NNODES) part[i] = sm[t] - v;
    if (t == 255) bsum[b] = sm[255];
}

__global__ void k_scan_top(int* __restrict__ bsum) {
    __shared__ int sm[256];
    int t = threadIdx.x;
    int v = (t < SCAN_B) ? bsum[t] : 0;
    sm[t] = v; __syncthreads();
    for (int off = 1; off < 256; off <<= 1) {
        int u = (t >= off) ? sm[t - off] : 0;
        __syncthreads();
        sm[t] += u; __syncthreads();
    }
    if (t < SCAN_B) bsum[t] = sm[t] - v;
}

__global__ void k_scan_add(const int* __restrict__ part, const int* __restrict__ bsum,
                           int* __restrict__ rs, int* __restrict__ cur) {
    int b = blockIdx.x, t = threadIdx.x, i = b * 256 + t;
    if (i < NNODES) { int r = part[i] + bsum[b]; rs[i] = r; cur[i] = r; }
}

__global__ void k_scatter(const int* __restrict__ ei, const int* __restrict__ flag,
                          int* __restrict__ cur, int* __restrict__ csr) {
    int e = blockIdx.x * 256 + threadIdx.x;    // exactly 800000
    int s, d;
    if (flag[0]) { s = ei[2 * e]; d = ei[2 * ERAW + 2 * e]; }
    else         { s = ei[e];     d = ei[ERAW + e]; }
    int pos = atomicAdd(&cur[d], 1);
    csr[pos] = s;
}

// ---------------- dense compute ----------------
// xb = bf16(x), one pass
__global__ void k_cast_x(const float* __restrict__ x, unsigned short* __restrict__ xb) {
    int i = blockIdx.x * 256 + threadIdx.x;    // 3,200,000 float4 groups
    float4 v = *(const float4*)(x + (size_t)i * 4);
    ushort4 o;
    o.x = f2b(v.x); o.y = f2b(v.y); o.z = f2b(v.z); o.w = f2b(v.w);
    *(ushort4*)(xb + (size_t)i * 4) = o;
}

// dst[n*K+k] = bf16(src[k*N+n]); grid: N blocks, K threads
__global__ void k_tr(const float* __restrict__ src, unsigned short* __restrict__ dst,
                     int K, int N) {
    int n = blockIdx.x, k = threadIdx.x;
    dst[n * K + k] = f2b(src[k * N + n]);
}

// xp = xb @ Wt^T with fused a_s/a_d epilogue (fp32 accum -> exact scores).
// Block: 64 rows x 512 cols, 8 waves (wave = 64 rows x 64 cols), A in LDS.
__global__ void __launch_bounds__(512)
k_gemm_xp(const unsigned short* __restrict__ xb,
          const unsigned short* __restrict__ Wt,
          const float* __restrict__ att_src, const float* __restrict__ att_dst,
          unsigned short* __restrict__ xp,
          float* __restrict__ a_s, float* __restrict__ a_d) {
    __shared__ unsigned short As[64 * LDSP];
    int bid = blockIdx.x;                      // 0..781
    int row0 = bid * 64;
    int tid = threadIdx.x;
    int w = tid >> 6, lane = tid & 63;
    int r = lane & 15, quad = lane >> 4;

    // stage 64x256 A tile (rows may read past xb into Wt region: benign bf16)
    {
        int row = tid >> 3, ch0 = tid & 7;     // 64 rows x 8 chunk-slots
        const uint4* g = (const uint4*)(xb + (size_t)(row0 + row) * DIN);
        uint4* l = (uint4*)(As + row * LDSP);
        #pragma unroll
        for (int i = 0; i < 4; ++i) {
            int ch = ch0 + i * 8;              // 32 uint4 per row
            l[ch] = g[ch];
        }
    }
    __syncthreads();

    f32x4 acc[4][4] = {};
    #pragma unroll
    for (int kc = 0; kc < 8; ++kc) {
        bf16x8 a[4], b[4];
        #pragma unroll
        for (int sub = 0; sub < 4; ++sub)
            a[sub] = *(const bf16x8*)(As + (sub * 16 + r) * LDSP + kc * 32 + quad * 8);
        #pragma unroll
        for (int t = 0; t < 4; ++t) {
            int col = w * 64 + t * 16 + r;
            b[t] = *(const bf16x8*)(Wt + (size_t)col * DIN + kc * 32 + quad * 8);
        }
        #pragma unroll
        for (int t = 0; t < 4; ++t)
            #pragma unroll
            for (int sub = 0; sub < 4; ++sub)
                acc[sub][t] = __builtin_amdgcn_mfma_f32_16x16x32_bf16(a[sub], b[t], acc[sub][t], 0, 0, 0);
    }

    // epilogue: store bf16 xp + fused attention scores
    float sS[4], sD[4];
    #pragma unroll
    for (int t = 0; t < 4; ++t) {
        int h = (w << 2) + t;
        sS[t] = att_src[h * CDIM + r];
        sD[t] = att_dst[h * CDIM + r];
    }
    #pragma unroll
    for (int sub = 0; sub < 4; ++sub) {
        #pragma unroll
        for (int t = 0; t < 4; ++t) {
            int col = w * 64 + t * 16 + r;
            #pragma unroll
            for (int j = 0; j < 4; ++j) {
                int row = row0 + sub * 16 + quad * 4 + j;
                float v = acc[sub][t][j];
                if (row < NNODES) xp[(size_t)row * NH + col] = f2b(v);
                float ps = v * sS[t], pd = v * sD[t];
                #pragma unroll
                for (int m = 1; m <= 8; m <<= 1) {
                    ps += __shfl_xor(ps, m, 64);
                    pd += __shfl_xor(pd, m, 64);
                }
                if (r == 0 && row < NNODES) {
                    int h = (w << 2) + t;
                    a_s[row * HEADS + h] = ps;
                    a_d[row * HEADS + h] = pd;
                }
            }
        }
    }
}

// One wave per dst node; single merged pass, unroll 8 for MLP.
__global__ void k_conv(const int* __restrict__ csr, const int* __restrict__ rs,
                       const int* __restrict__ deg,
                       const unsigned short* __restrict__ xp,
                       const float* __restrict__ a_s, const float* __restrict__ a_d,
                       const float* __restrict__ bias, float* __restrict__ out) {
    int w = blockIdx.x * 4 + (threadIdx.x >> 6);       // exactly 50000
    int lane = threadIdx.x & 63;
    int h2 = lane >> 1;
    float adn = a_d[w * HEADS + h2];
    int beg = __builtin_amdgcn_readfirstlane(rs[w]);
    int cnt = __builtin_amdgcn_readfirstlane(deg[w]);

    float denom = 0.f;
    float acc[8] = {0, 0, 0, 0, 0, 0, 0, 0};

    {   // self contribution
        float t = a_s[w * HEADS + h2] + adn;
        t = t > 0.f ? t : 0.2f * t;
        float e = __expf(t);
        denom += e;
        const uint4 q = *(const uint4*)(xp + (size_t)w * NH + lane * 8);
        unsigned u[4] = {q.x, q.y, q.z, q.w};
        #pragma unroll
        for (int j = 0; j < 4; ++j) {
            acc[2 * j]     += e * b2f((unsigned short)(u[j] & 0xffff));
            acc[2 * j + 1] += e * b2f((unsigned short)(u[j] >> 16));
        }
    }

    int i = 0;
    for (; i + 8 <= cnt; i += 8) {
        int sv[8];
        #pragma unroll
        for (int k = 0; k < 8; ++k) sv[k] = csr[beg + i + k];
        float av[8];
        #pragma unroll
        for (int k = 0; k < 8; ++k) av[k] = a_s[sv[k] * HEADS + h2];
        uint4 qv[8];
        #pragma unroll
        for (int k = 0; k < 8; ++k) qv[k] = *(const uint4*)(xp + (size_t)sv[k] * NH + lane * 8);
        #pragma unroll
        for (int k = 0; k < 8; ++k) {
            float t = av[k] + adn;
            t = t > 0.f ? t : 0.2f * t;
            float e = __expf(t);
            denom += e;
            unsigned u[4] = {qv[k].x, qv[k].y, qv[k].z, qv[k].w};
            #pragma unroll
            for (int j = 0; j < 4; ++j) {
                acc[2 * j]     += e * b2f((unsigned short)(u[j] & 0xffff));
                acc[2 * j + 1] += e * b2f((unsigned short)(u[j] >> 16));
            }
        }
    }
    for (; i + 4 <= cnt; i += 4) {
        int sv[4];
        #pragma unroll
        for (int k = 0; k < 4; ++k) sv[k] = csr[beg + i + k];
        float av[4];
        #pragma unroll
        for (int k = 0; k < 4; ++k) av[k] = a_s[sv[k] * HEADS + h2];
        uint4 qv[4];
        #pragma unroll
        for (int k = 0; k < 4; ++k) qv[k] = *(const uint4*)(xp + (size_t)sv[k] * NH + lane * 8);
        #pragma unroll
        for (int k = 0; k < 4; ++k) {
            float t = av[k] + adn;
            t = t > 0.f ? t : 0.2f * t;
            float e = __expf(t);
            denom += e;
            unsigned u[4] = {qv[k].x, qv[k].y, qv[k].z, qv[k].w};
            #pragma unroll
            for (int j = 0; j < 4; ++j) {
                acc[2 * j]     += e * b2f((unsigned short)(u[j] & 0xffff));
                acc[2 * j + 1] += e * b2f((unsigned short)(u[j] >> 16));
            }
        }
    }
    for (; i < cnt; ++i) {
        int s = csr[beg + i];
        float t = a_s[s * HEADS + h2] + adn;
        t = t > 0.f ? t : 0.2f * t;
        float e = __expf(t);
        denom += e;
        const uint4 q = *(const uint4*)(xp + (size_t)s * NH + lane * 8);
        unsigned u[4] = {q.x, q.y, q.z, q.w};
        #pragma unroll
        for (int j = 0; j < 4; ++j) {
            acc[2 * j]     += e * b2f((unsigned short)(u[j] & 0xffff));
            acc[2 * j + 1] += e * b2f((unsigned short)(u[j] >> 16));
        }
    }

    float inv = 1.f / (denom + 1e-16f);
    #pragma unroll
    for (int j = 0; j < 8; ++j) acc[j] *= inv;

    #pragma unroll
    for (int m = 2; m <= 32; m <<= 1) {
        #pragma unroll
        for (int j = 0; j < 8; ++j) acc[j] += __shfl_xor(acc[j], m, 64);
    }
    if (lane < 2) {
        #pragma unroll
        for (int j = 0; j < 8; ++j) {
            int c = lane * 8 + j;
            float o = acc[j] * (1.0f / HEADS) + bias[c];
            out[(size_t)w * CDIM + c] = o > 0.f ? o : expm1f(o);
        }
    }
}

// x1 = elu(xb @ w1t + b1); wave = 64 rows x 64 cols; 782 active waves
__global__ void k_mlp1(const unsigned short* __restrict__ xb,
                       const unsigned short* __restrict__ w1t,
                       const float* __restrict__ bb1, unsigned short* __restrict__ x1) {
    int wave = blockIdx.x * 4 + (threadIdx.x >> 6);
    if (wave >= 782) return;
    int lane = threadIdx.x & 63;
    int r = lane & 15, quad = lane >> 4;
    int row0 = wave * 64;

    f32x4 acc[4][4] = {};
    #pragma unroll
    for (int kc = 0; kc < 8; ++kc) {
        bf16x8 a[4];
        #pragma unroll
        for (int sub = 0; sub < 4; ++sub) {
            int row = row0 + sub * 16 + r;
            if (row0 + sub * 16 < NNODES)      // wave-uniform; tail rows read in-bounds-ish
                a[sub] = *(const bf16x8*)(xb + (size_t)row * DIN + kc * 32 + quad * 8);
            else {
                union { unsigned short u[8]; bf16x8 v; } z;
                #pragma unroll
                for (int j = 0; j < 8; ++j) z.u[j] = 0;
                a[sub] = z.v;
            }
        }
        #pragma unroll
        for (int t = 0; t < 4; ++t) {
            int col = t * 16 + r;
            bf16x8 b = *(const bf16x8*)(w1t + (size_t)col * DIN + kc * 32 + quad * 8);
            #pragma unroll
            for (int sub = 0; sub < 4; ++sub)
                acc[sub][t] = __builtin_amdgcn_mfma_f32_16x16x32_bf16(a[sub], b, acc[sub][t], 0, 0, 0);
        }
    }
    #pragma unroll
    for (int sub = 0; sub < 4; ++sub) {
        #pragma unroll
        for (int t = 0; t < 4; ++t) {
            int col = t * 16 + r;
            float bv = bb1[col];
            #pragma unroll
            for (int j = 0; j < 4; ++j) {
                int row = row0 + sub * 16 + quad * 4 + j;
                if (row < NNODES) {
                    float v = acc[sub][t][j] + bv;
                    v = v > 0.f ? v : expm1f(v);
                    x1[(size_t)row * 64 + col] = f2b(v);
                }
            }
        }
    }
}

// out = elu(x1 @ w2t + b2); wave = 16 rows x 16 cols; 3125 active waves
__global__ void k_mlp2(const unsigned short* __restrict__ x1,
                       const unsigned short* __restrict__ w2t,
                       const float* __restrict__ bb2, float* __restrict__ out) {
    int wave = blockIdx.x * 4 + (threadIdx.x >> 6);
    if (wave >= 3125) return;
    int lane = threadIdx.x & 63;
    int r = lane & 15, quad = lane >> 4;

    f32x4 acc = {};
    #pragma unroll
    for (int kc = 0; kc < 2; ++kc) {
        bf16x8 a = *(const bf16x8*)(x1 + (size_t)(wave * 16 + r) * 64 + kc * 32 + quad * 8);
        bf16x8 b = *(const bf16x8*)(w2t + (size_t)r * 64 + kc * 32 + quad * 8);
        acc = __builtin_amdgcn_mfma_f32_16x16x32_bf16(a, b, acc, 0, 0, 0);
    }
    float bv = bb2[r];
    #pragma unroll
    for (int j = 0; j < 4; ++j) {
        int row = wave * 16 + quad * 4 + j;
        float v = acc[j] + bv;
        v = v > 0.f ? v : expm1f(v);
        out[(size_t)row * CDIM + r] = v;
    }
}

extern "C" void kernel_launch(void* const* d_in, const int* in_sizes, int n_in,
                              void* d_out, int out_size, void* d_ws, size_t ws_size,
                              hipStream_t stream) {
    const float* x  = (const float*)d_in[0];
    const int* ei   = (const int*)d_in[1];
    const float* W[2]    = {(const float*)d_in[2], (const float*)d_in[6]};
    const float* atS[2]  = {(const float*)d_in[3], (const float*)d_in[7]};
    const float* atD[2]  = {(const float*)d_in[4], (const float*)d_in[8]};
    const float* bias[2] = {(const float*)d_in[5], (const float*)d_in[9]};
    const float* w1 = (const float*)d_in[10];
    const float* b1 = (const float*)d_in[11];
    const float* w2 = (const float*)d_in[12];
    const float* b2 = (const float*)d_in[13];
    float* out = (float*)d_out;

    char* ws = (char*)d_ws;
    unsigned short* xp  = (unsigned short*)(ws);              // 51,200,000 B
    unsigned short* xb  = (unsigned short*)(ws + 51200000);   // 25,600,000 B
    unsigned short* Wt  = (unsigned short*)(ws + 76800000);   //    262,144 B (xb tail-read spills here: benign bf16)
    unsigned short* w1t = (unsigned short*)(ws + 77062144);   //     32,768 B
    unsigned short* w2t = (unsigned short*)(ws + 77094912);   //      2,048 B
    float* a_s = (float*)(ws + 77096960);                     //  6,400,000 B
    float* a_d = (float*)(ws + 83496960);                     //  6,400,000 B
    unsigned short* x1 = (unsigned short*)(ws + 77096960);    // alias a_s (dead before mlp1)
    int* deg   = (int*)(ws + 89896960);                       //    200,000 B
    int* rs    = (int*)(ws + 90096960);                       //    200,000 B
    int* cur   = (int*)(ws + 90296960);                       //    200,000 B
    int* part  = (int*)(ws + 90496960);                       //    200,000 B
    int* bsum  = (int*)(ws + 90696960);                       //      1,024 B
    int* csr   = (int*)(ws + 90697984);                       //  3,200,000 B
    int* flag  = (int*)(ws + 93897984);                       //          4 B

    k_detect<<<1, 64, 0, stream>>>(ei, flag);
    k_zero_deg<<<SCAN_B, 256, 0, stream>>>(deg);
    k_hist    <<<3125, 256, 0, stream>>>(ei, flag, deg);
    k_scan_blk<<<SCAN_B, 256, 0, stream>>>(deg, part, bsum);
    k_scan_top<<<1, 256, 0, stream>>>(bsum);
    k_scan_add<<<SCAN_B, 256, 0, stream>>>(part, bsum, rs, cur);
    k_scatter <<<3125, 256, 0, stream>>>(ei, flag, cur, csr);

    k_cast_x<<<12500, 256, 0, stream>>>(x, xb);
    k_tr<<<64, 256, 0, stream>>>(w1, w1t, DIN, 64);
    k_tr<<<16, 64, 0, stream>>>(w2, w2t, 64, CDIM);

    for (int cv = 0; cv < 2; ++cv) {
        k_tr     <<<512, 256, 0, stream>>>(W[cv], Wt, DIN, NH);
        k_gemm_xp<<<782, 512, 0, stream>>>(xb, Wt, atS[cv], atD[cv], xp, a_s, a_d);
        k_conv   <<<12500, 256, 0, stream>>>(csr, rs, deg, xp, a_s, a_d,
                                             bias[cv], out + (size_t)cv * 800000);
    }
    k_mlp1<<<196, 256, 0, stream>>>(xb, w1t, b1, x1);
    k_mlp2<<<782, 256, 0, stream>>>(x1, w2t, b2, out + 1600000);
}

// Round 7
// 623.433 us; speedup vs baseline: 2.4197x; 1.1038x over previous
//
#include <hip/hip_runtime.h>

typedef __bf16 bf16x8 __attribute__((ext_vector_type(8)));
typedef float  f32x4  __attribute__((ext_vector_type(4)));

#define NNODES   50000
#define DIN      256
#define HEADS    32
#define CDIM     16
#define NH       512          // HEADS*CDIM
#define ERAW     800000
#define SCAN_B   196          // ceil(50000/256)
#define LDSW     280          // padded A-row in bf16: r-stride 140 dw -> 2-way bank alias (free)

__device__ __forceinline__ float b2f(unsigned short u) {
    return __uint_as_float(((unsigned)u) << 16);
}
__device__ __forceinline__ unsigned short f2b(float f) {
    unsigned v = __float_as_uint(f);
    v += 0x7fffu + ((v >> 16) & 1u);           // RNE
    return (unsigned short)(v >> 16);
}

// probe edge_index width: int64 -> odd int32 slots are high words == 0
__global__ void k_detect(const int* __restrict__ ei, int* __restrict__ flag) {
    if (threadIdx.x == 0 && blockIdx.x == 0) {
        int nz = 0;
        #pragma unroll
        for (int t = 0; t < 64; ++t) nz |= ei[2 * t + 1];
        flag[0] = (nz == 0) ? 1 : 0;           // 1 => int64
    }
}

// ---------------- CSR build (dst-sorted), raw edges only ----------------
__global__ void k_zero_deg(int* __restrict__ deg) {
    int i = blockIdx.x * 256 + threadIdx.x;
    if (i < NNODES) deg[i] = 0;
}

__global__ void k_hist(const int* __restrict__ ei, const int* __restrict__ flag,
                       int* __restrict__ deg) {
    int e = blockIdx.x * 256 + threadIdx.x;    // exactly 800000
    int d = flag[0] ? ei[2 * ERAW + 2 * e] : ei[ERAW + e];
    atomicAdd(&deg[d], 1);
}

__global__ void k_scan_blk(const int* __restrict__ deg, int* __restrict__ part,
                           int* __restrict__ bsum) {
    __shared__ int sm[256];
    int b = blockIdx.x, t = threadIdx.x, i = b * 256 + t;
    int v = (i < NNODES) ? deg[i] : 0;
    sm[t] = v; __syncthreads();
    for (int off = 1; off < 256; off <<= 1) {
        int u = (t >= off) ? sm[t - off] : 0;
        __syncthreads();
        sm[t] += u; __syncthreads();
    }
    if (i < NNODES) part[i] = sm[t] - v;
    if (t == 255) bsum[b] = sm[255];
}

__global__ void k_scan_top(int* __restrict__ bsum) {
    __shared__ int sm[256];
    int t = threadIdx.x;
    int v = (t < SCAN_B) ? bsum[t] : 0;
    sm[t] = v; __syncthreads();
    for (int off = 1; off < 256; off <<= 1) {
        int u = (t >= off) ? sm[t - off] : 0;
        __syncthreads();
        sm[t] += u; __syncthreads();
    }
    if (t < SCAN_B) bsum[t] = sm[t] - v;
}

__global__ void k_scan_add(const int* __restrict__ part, const int* __restrict__ bsum,
                           int* __restrict__ rs, int* __restrict__ cur) {
    int b = blockIdx.x, t = threadIdx.x, i = b * 256 + t;
    if (i < NNODES) { int r = part[i] + bsum[b]; rs[i] = r; cur[i] = r; }
}

__global__ void k_scatter(const int* __restrict__ ei, const int* __restrict__ flag,
                          int* __restrict__ cur, int* __restrict__ csr) {
    int e = blockIdx.x * 256 + threadIdx.x;    // exactly 800000
    int s, d;
    if (flag[0]) { s = ei[2 * e]; d = ei[2 * ERAW + 2 * e]; }
    else         { s = ei[e];     d = ei[ERAW + e]; }
    int pos = atomicAdd(&cur[d], 1);
    csr[pos] = s;
}

// ---------------- dense compute ----------------
// xb = bf16(x), one pass
__global__ void k_cast_x(const float* __restrict__ x, unsigned short* __restrict__ xb) {
    int i = blockIdx.x * 256 + threadIdx.x;    // 3,200,000 float4 groups
    float4 v = *(const float4*)(x + (size_t)i * 4);
    ushort4 o;
    o.x = f2b(v.x); o.y = f2b(v.y); o.z = f2b(v.z); o.w = f2b(v.w);
    *(ushort4*)(xb + (size_t)i * 4) = o;
}

// dst[n*K+k] = bf16(src[k*N+n]); grid: N blocks, K threads
__global__ void k_tr(const float* __restrict__ src, unsigned short* __restrict__ dst,
                     int K, int N) {
    int n = blockIdx.x, k = threadIdx.x;
    dst[n * K + k] = f2b(src[k * N + n]);
}

// xp = xb @ Wt^T. Block: 64 rows x 512 cols (4 waves), A-panel staged once in
// LDS (whole K=256), two col-half passes reusing acc registers. B is L2-hot.
__global__ void __launch_bounds__(256)
k_gemm_xp(const unsigned short* __restrict__ xb,
          const unsigned short* __restrict__ Wt,
          unsigned short* __restrict__ xp) {
    __shared__ unsigned short As[64 * LDSW];
    int row0 = blockIdx.x * 64;                // 782 blocks
    int tid = threadIdx.x;
    int w = tid >> 6, lane = tid & 63;
    int r = lane & 15, quad = lane >> 4;

    {   // stage 64 rows x 256 bf16 (512 B = 32 uint4 per row); 4 threads/row x 8 uint4
        int row = tid >> 2, slot = tid & 3;
        const uint4* g = (const uint4*)(xb + (size_t)(row0 + row) * DIN);
        uint4* l = (uint4*)(As + row * LDSW);  // 560 B stride, 16B-aligned
        #pragma unroll
        for (int i = 0; i < 8; ++i)
            l[slot + 4 * i] = g[slot + 4 * i];
    }
    __syncthreads();

    #pragma unroll
    for (int ch = 0; ch < 2; ++ch) {           // col halves: 256 cols each
        f32x4 acc[4][4] = {};
        #pragma unroll
        for (int kc = 0; kc < 8; ++kc) {
            bf16x8 a[4], b[4];
            #pragma unroll
            for (int sub = 0; sub < 4; ++sub)
                a[sub] = *(const bf16x8*)(As + (sub * 16 + r) * LDSW + kc * 32 + quad * 8);
            #pragma unroll
            for (int t = 0; t < 4; ++t) {
                int col = ch * 256 + w * 64 + t * 16 + r;
                b[t] = *(const bf16x8*)(Wt + (size_t)col * DIN + kc * 32 + quad * 8);
            }
            #pragma unroll
            for (int t = 0; t < 4; ++t)
                #pragma unroll
                for (int sub = 0; sub < 4; ++sub)
                    acc[sub][t] = __builtin_amdgcn_mfma_f32_16x16x32_bf16(a[sub], b[t], acc[sub][t], 0, 0, 0);
        }
        #pragma unroll
        for (int sub = 0; sub < 4; ++sub) {
            #pragma unroll
            for (int t = 0; t < 4; ++t) {
                int col = ch * 256 + w * 64 + t * 16 + r;
                #pragma unroll
                for (int j = 0; j < 4; ++j) {
                    int row = row0 + sub * 16 + quad * 4 + j;
                    if (row < NNODES)
                        xp[(size_t)row * NH + col] = f2b(acc[sub][t][j]);
                }
            }
        }
    }
}

// a_s[n,h] = sum_c xp[n,h,c]*att_src[h,c]; vectorized uint4 loads
__global__ void k_att(const unsigned short* __restrict__ xp,
                      const float* __restrict__ att_src,
                      const float* __restrict__ att_dst,
                      float* __restrict__ a_s, float* __restrict__ a_d) {
    int idx = blockIdx.x * 256 + threadIdx.x;          // exactly 1,600,000
    int h = idx & 31;
    const uint4* row = (const uint4*)(xp + (size_t)idx * CDIM);
    uint4 q0 = row[0], q1 = row[1];
    unsigned u[8] = {q0.x, q0.y, q0.z, q0.w, q1.x, q1.y, q1.z, q1.w};
    float s = 0.f, d = 0.f;
    #pragma unroll
    for (int j = 0; j < 8; ++j) {
        float v0 = b2f((unsigned short)(u[j] & 0xffff));
        float v1 = b2f((unsigned short)(u[j] >> 16));
        s += v0 * att_src[h * CDIM + 2 * j] + v1 * att_src[h * CDIM + 2 * j + 1];
        d += v0 * att_dst[h * CDIM + 2 * j] + v1 * att_dst[h * CDIM + 2 * j + 1];
    }
    a_s[idx] = s;
    a_d[idx] = d;
}

// One wave per dst node; single merged pass, unroll 8 for MLP.
__global__ void k_conv(const int* __restrict__ csr, const int* __restrict__ rs,
                       const int* __restrict__ deg,
                       const unsigned short* __restrict__ xp,
                       const float* __restrict__ a_s, const float* __restrict__ a_d,
                       const float* __restrict__ bias, float* __restrict__ out) {
    int w = blockIdx.x * 4 + (threadIdx.x >> 6);       // exactly 50000
    int lane = threadIdx.x & 63;
    int h2 = lane >> 1;
    float adn = a_d[w * HEADS + h2];
    int beg = __builtin_amdgcn_readfirstlane(rs[w]);
    int cnt = __builtin_amdgcn_readfirstlane(deg[w]);

    float denom = 0.f;
    float acc[8] = {0, 0, 0, 0, 0, 0, 0, 0};

    {   // self contribution
        float t = a_s[w * HEADS + h2] + adn;
        t = t > 0.f ? t : 0.2f * t;
        float e = __expf(t);
        denom += e;
        const uint4 q = *(const uint4*)(xp + (size_t)w * NH + lane * 8);
        unsigned u[4] = {q.x, q.y, q.z, q.w};
        #pragma unroll
        for (int j = 0; j < 4; ++j) {
            acc[2 * j]     += e * b2f((unsigned short)(u[j] & 0xffff));
            acc[2 * j + 1] += e * b2f((unsigned short)(u[j] >> 16));
        }
    }

    int i = 0;
    for (; i + 8 <= cnt; i += 8) {
        int sv[8];
        #pragma unroll
        for (int k = 0; k < 8; ++k) sv[k] = csr[beg + i + k];
        float av[8];
        #pragma unroll
        for (int k = 0; k < 8; ++k) av[k] = a_s[sv[k] * HEADS + h2];
        uint4 qv[8];
        #pragma unroll
        for (int k = 0; k < 8; ++k) qv[k] = *(const uint4*)(xp + (size_t)sv[k] * NH + lane * 8);
        #pragma unroll
        for (int k = 0; k < 8; ++k) {
            float t = av[k] + adn;
            t = t > 0.f ? t : 0.2f * t;
            float e = __expf(t);
            denom += e;
            unsigned u[4] = {qv[k].x, qv[k].y, qv[k].z, qv[k].w};
            #pragma unroll
            for (int j = 0; j < 4; ++j) {
                acc[2 * j]     += e * b2f((unsigned short)(u[j] & 0xffff));
                acc[2 * j + 1] += e * b2f((unsigned short)(u[j] >> 16));
            }
        }
    }
    for (; i + 4 <= cnt; i += 4) {
        int sv[4];
        #pragma unroll
        for (int k = 0; k < 4; ++k) sv[k] = csr[beg + i + k];
        float av[4];
        #pragma unroll
        for (int k = 0; k < 4; ++k) av[k] = a_s[sv[k] * HEADS + h2];
        uint4 qv[4];
        #pragma unroll
        for (int k = 0; k < 4; ++k) qv[k] = *(const uint4*)(xp + (size_t)sv[k] * NH + lane * 8);
        #pragma unroll
        for (int k = 0; k < 4; ++k) {
            float t = av[k] + adn;
            t = t > 0.f ? t : 0.2f * t;
            float e = __expf(t);
            denom += e;
            unsigned u[4] = {qv[k].x, qv[k].y, qv[k].z, qv[k].w};
            #pragma unroll
            for (int j = 0; j < 4; ++j) {
                acc[2 * j]     += e * b2f((unsigned short)(u[j] & 0xffff));
                acc[2 * j + 1] += e * b2f((unsigned short)(u[j] >> 16));
            }
        }
    }
    for (; i < cnt; ++i) {
        int s = csr[beg + i];
        float t = a_s[s * HEADS + h2] + adn;
        t = t > 0.f ? t : 0.2f * t;
        float e = __expf(t);
        denom += e;
        const uint4 q = *(const uint4*)(xp + (size_t)s * NH + lane * 8);
        unsigned u[4] = {q.x, q.y, q.z, q.w};
        #pragma unroll
        for (int j = 0; j < 4; ++j) {
            acc[2 * j]     += e * b2f((unsigned short)(u[j] & 0xffff));
            acc[2 * j + 1] += e * b2f((unsigned short)(u[j] >> 16));
        }
    }

    float inv = 1.f / (denom + 1e-16f);
    #pragma unroll
    for (int j = 0; j < 8; ++j) acc[j] *= inv;

    #pragma unroll
    for (int m = 2; m <= 32; m <<= 1) {
        #pragma unroll
        for (int j = 0; j < 8; ++j) acc[j] += __shfl_xor(acc[j], m, 64);
    }
    if (lane < 2) {
        #pragma unroll
        for (int j = 0; j < 8; ++j) {
            int c = lane * 8 + j;
            float o = acc[j] * (1.0f / HEADS) + bias[c];
            out[(size_t)w * CDIM + c] = o > 0.f ? o : expm1f(o);
        }
    }
}

// x1 = elu(xb @ w1t + b1); wave = 64 rows x 64 cols; 782 active waves
__global__ void k_mlp1(const unsigned short* __restrict__ xb,
                       const unsigned short* __restrict__ w1t,
                       const float* __restrict__ bb1, unsigned short* __restrict__ x1) {
    int wave = blockIdx.x * 4 + (threadIdx.x >> 6);
    if (wave >= 782) return;
    int lane = threadIdx.x & 63;
    int r = lane & 15, quad = lane >> 4;
    int row0 = wave * 64;

    f32x4 acc[4][4] = {};
    #pragma unroll
    for (int kc = 0; kc < 8; ++kc) {
        bf16x8 a[4];
        #pragma unroll
        for (int sub = 0; sub < 4; ++sub) {
            int row = row0 + sub * 16 + r;
            if (row0 + sub * 16 < NNODES)
                a[sub] = *(const bf16x8*)(xb + (size_t)row * DIN + kc * 32 + quad * 8);
            else {
                union { unsigned short u[8]; bf16x8 v; } z;
                #pragma unroll
                for (int j = 0; j < 8; ++j) z.u[j] = 0;
                a[sub] = z.v;
            }
        }
        #pragma unroll
        for (int t = 0; t < 4; ++t) {
            int col = t * 16 + r;
            bf16x8 b = *(const bf16x8*)(w1t + (size_t)col * DIN + kc * 32 + quad * 8);
            #pragma unroll
            for (int sub = 0; sub < 4; ++sub)
                acc[sub][t] = __builtin_amdgcn_mfma_f32_16x16x32_bf16(a[sub], b, acc[sub][t], 0, 0, 0);
        }
    }
    #pragma unroll
    for (int sub = 0; sub < 4; ++sub) {
        #pragma unroll
        for (int t = 0; t < 4; ++t) {
            int col = t * 16 + r;
            float bv = bb1[col];
            #pragma unroll
            for (int j = 0; j < 4; ++j) {
                int row = row0 + sub * 16 + quad * 4 + j;
                if (row < NNODES) {
                    float v = acc[sub][t][j] + bv;
                    v = v > 0.f ? v : expm1f(v);
                    x1[(size_t)row * 64 + col] = f2b(v);
                }
            }
        }
    }
}

// out = elu(x1 @ w2t + b2); wave = 16 rows x 16 cols; 3125 active waves
__global__ void k_mlp2(const unsigned short* __restrict__ x1,
                       const unsigned short* __restrict__ w2t,
                       const float* __restrict__ bb2, float* __restrict__ out) {
    int wave = blockIdx.x * 4 + (threadIdx.x >> 6);
    if (wave >= 3125) return;
    int lane = threadIdx.x & 63;
    int r = lane & 15, quad = lane >> 4;

    f32x4 acc = {};
    #pragma unroll
    for (int kc = 0; kc < 2; ++kc) {
        bf16x8 a = *(const bf16x8*)(x1 + (size_t)(wave * 16 + r) * 64 + kc * 32 + quad * 8);
        bf16x8 b = *(const bf16x8*)(w2t + (size_t)r * 64 + kc * 32 + quad * 8);
        acc = __builtin_amdgcn_mfma_f32_16x16x32_bf16(a, b, acc, 0, 0, 0);
    }
    float bv = bb2[r];
    #pragma unroll
    for (int j = 0; j < 4; ++j) {
        int row = wave * 16 + quad * 4 + j;
        float v = acc[j] + bv;
        v = v > 0.f ? v : expm1f(v);
        out[(size_t)row * CDIM + r] = v;
    }
}

extern "C" void kernel_launch(void* const* d_in, const int* in_sizes, int n_in,
                              void* d_out, int out_size, void* d_ws, size_t ws_size,
                              hipStream_t stream) {
    const float* x  = (const float*)d_in[0];
    const int* ei   = (const int*)d_in[1];
    const float* W[2]    = {(const float*)d_in[2], (const float*)d_in[6]};
    const float* atS[2]  = {(const float*)d_in[3], (const float*)d_in[7]};
    const float* atD[2]  = {(const float*)d_in[4], (const float*)d_in[8]};
    const float* bias[2] = {(const float*)d_in[5], (const float*)d_in[9]};
    const float* w1 = (const float*)d_in[10];
    const float* b1 = (const float*)d_in[11];
    const float* w2 = (const float*)d_in[12];
    const float* b2 = (const float*)d_in[13];
    float* out = (float*)d_out;

    char* ws = (char*)d_ws;
    unsigned short* xp  = (unsigned short*)(ws);              // 51,200,000 B
    unsigned short* xb  = (unsigned short*)(ws + 51200000);   // 25,600,000 B
    unsigned short* Wt  = (unsigned short*)(ws + 76800000);   //    262,144 B (xb tail-read spills here: benign bf16)
    unsigned short* w1t = (unsigned short*)(ws + 77062144);   //     32,768 B
    unsigned short* w2t = (unsigned short*)(ws + 77094912);   //      2,048 B
    float* a_s = (float*)(ws + 77096960);                     //  6,400,000 B
    float* a_d = (float*)(ws + 83496960);                     //  6,400,000 B
    unsigned short* x1 = (unsigned short*)(ws + 77096960);    // alias a_s (dead before mlp1)
    int* deg   = (int*)(ws + 89896960);                       //    200,000 B
    int* rs    = (int*)(ws + 90096960);                       //    200,000 B
    int* cur   = (int*)(ws + 90296960);                       //    200,000 B
    int* part  = (int*)(ws + 90496960);                       //    200,000 B
    int* bsum  = (int*)(ws + 90696960);                       //      1,024 B
    int* csr   = (int*)(ws + 90697984);                       //  3,200,000 B
    int* flag  = (int*)(ws + 93897984);                       //          4 B

    k_detect<<<1, 64, 0, stream>>>(ei, flag);
    k_zero_deg<<<SCAN_B, 256, 0, stream>>>(deg);
    k_hist    <<<3125, 256, 0, stream>>>(ei, flag, deg);
    k_scan_blk<<<SCAN_B, 256, 0, stream>>>(deg, part, bsum);
    k_scan_top<<<1, 256, 0, stream>>>(bsum);
    k_scan_add<<<SCAN_B, 256, 0, stream>>>(part, bsum, rs, cur);
    k_scatter <<<3125, 256, 0, stream>>>(ei, flag, cur, csr);

    k_cast_x<<<12500, 256, 0, stream>>>(x, xb);
    k_tr<<<64, 256, 0, stream>>>(w1, w1t, DIN, 64);
    k_tr<<<16, 64, 0, stream>>>(w2, w2t, 64, CDIM);

    for (int cv = 0; cv < 2; ++cv) {
        k_tr     <<<512, 256, 0, stream>>>(W[cv], Wt, DIN, NH);
        k_gemm_xp<<<782, 256, 0, stream>>>(xb, Wt, xp);
        k_att    <<<6250, 256, 0, stream>>>(xp, atS[cv], atD[cv], a_s, a_d);
        k_conv   <<<12500, 256, 0, stream>>>(csr, rs, deg, xp, a_s, a_d,
                                             bias[cv], out + (size_t)cv * 800000);
    }
    k_mlp1<<<196, 256, 0, stream>>>(xb, w1t, b1, x1);
    k_mlp2<<<782, 256, 0, stream>>>(x1, w2t, b2, out + 1600000);
}

// Round 8
// 511.237 us; speedup vs baseline: 2.9507x; 1.2195x over previous
//
#include <hip/hip_runtime.h>

typedef __bf16 bf16x8 __attribute__((ext_vector_type(8)));
typedef float  f32x4  __attribute__((ext_vector_type(4)));
typedef float  f32x2  __attribute__((ext_vector_type(2)));

#define NNODES   50000
#define DIN      256
#define HEADS    32
#define CDIM     16
#define NH       512          // HEADS*CDIM
#define ERAW     800000
#define SCAN_B   196          // ceil(50000/256)
#define LDSW     280          // padded A-row in bf16: r-stride 140 dw -> 2-way bank alias (free)

__device__ __forceinline__ float b2f(unsigned short u) {
    return __uint_as_float(((unsigned)u) << 16);
}
__device__ __forceinline__ unsigned short f2b(float f) {
    unsigned v = __float_as_uint(f);
    v += 0x7fffu + ((v >> 16) & 1u);           // RNE
    return (unsigned short)(v >> 16);
}

// probe edge_index width: int64 -> odd int32 slots are high words == 0
__global__ void k_detect(const int* __restrict__ ei, int* __restrict__ flag) {
    if (threadIdx.x == 0 && blockIdx.x == 0) {
        int nz = 0;
        #pragma unroll
        for (int t = 0; t < 64; ++t) nz |= ei[2 * t + 1];
        flag[0] = (nz == 0) ? 1 : 0;           // 1 => int64
    }
}

// ---------------- CSR build (dst-sorted), raw edges only ----------------
__global__ void k_zero_deg(int* __restrict__ deg) {
    int i = blockIdx.x * 256 + threadIdx.x;
    if (i < NNODES) deg[i] = 0;
}

__global__ void k_hist(const int* __restrict__ ei, const int* __restrict__ flag,
                       int* __restrict__ deg) {
    int e = blockIdx.x * 256 + threadIdx.x;    // exactly 800000
    int d = flag[0] ? ei[2 * ERAW + 2 * e] : ei[ERAW + e];
    atomicAdd(&deg[d], 1);
}

__global__ void k_scan_blk(const int* __restrict__ deg, int* __restrict__ part,
                           int* __restrict__ bsum) {
    __shared__ int sm[256];
    int b = blockIdx.x, t = threadIdx.x, i = b * 256 + t;
    int v = (i < NNODES) ? deg[i] : 0;
    sm[t] = v; __syncthreads();
    for (int off = 1; off < 256; off <<= 1) {
        int u = (t >= off) ? sm[t - off] : 0;
        __syncthreads();
        sm[t] += u; __syncthreads();
    }
    if (i < NNODES) part[i] = sm[t] - v;
    if (t == 255) bsum[b] = sm[255];
}

__global__ void k_scan_top(int* __restrict__ bsum) {
    __shared__ int sm[256];
    int t = threadIdx.x;
    int v = (t < SCAN_B) ? bsum[t] : 0;
    sm[t] = v; __syncthreads();
    for (int off = 1; off < 256; off <<= 1) {
        int u = (t >= off) ? sm[t - off] : 0;
        __syncthreads();
        sm[t] += u; __syncthreads();
    }
    if (t < SCAN_B) bsum[t] = sm[t] - v;
}

__global__ void k_scan_add(const int* __restrict__ part, const int* __restrict__ bsum,
                           int* __restrict__ rs, int* __restrict__ cur) {
    int b = blockIdx.x, t = threadIdx.x, i = b * 256 + t;
    if (i < NNODES) { int r = part[i] + bsum[b]; rs[i] = r; cur[i] = r; }
}

__global__ void k_scatter(const int* __restrict__ ei, const int* __restrict__ flag,
                          int* __restrict__ cur, int* __restrict__ csr) {
    int e = blockIdx.x * 256 + threadIdx.x;    // exactly 800000
    int s, d;
    if (flag[0]) { s = ei[2 * e]; d = ei[2 * ERAW + 2 * e]; }
    else         { s = ei[e];     d = ei[ERAW + e]; }
    int pos = atomicAdd(&cur[d], 1);
    csr[pos] = s;
}

// ---------------- dense compute ----------------
// xb = bf16(x), one pass
__global__ void k_cast_x(const float* __restrict__ x, unsigned short* __restrict__ xb) {
    int i = blockIdx.x * 256 + threadIdx.x;    // 3,200,000 float4 groups
    float4 v = *(const float4*)(x + (size_t)i * 4);
    ushort4 o;
    o.x = f2b(v.x); o.y = f2b(v.y); o.z = f2b(v.z); o.w = f2b(v.w);
    *(ushort4*)(xb + (size_t)i * 4) = o;
}

// dst[n*K+k] = bf16(src[k*N+n]); grid: N blocks, K threads
__global__ void k_tr(const float* __restrict__ src, unsigned short* __restrict__ dst,
                     int K, int N) {
    int n = blockIdx.x, k = threadIdx.x;
    dst[n * K + k] = f2b(src[k * N + n]);
}

// xp8 = fp8_e4m3(xb @ Wt^T), permuted layout: within each 64-col group,
// byte (r*4 + t) holds col (t*16 + r). Dword at row*128 + ch*64 + w*16 + r
// packs acc[t=0..3] for col t*16+r. Block: 64 rows x 512 cols (4 waves).
__global__ void __launch_bounds__(256)
k_gemm_xp(const unsigned short* __restrict__ xb,
          const unsigned short* __restrict__ Wt,
          unsigned* __restrict__ xp8) {
    __shared__ unsigned short As[64 * LDSW];
    int row0 = blockIdx.x * 64;                // 782 blocks
    int tid = threadIdx.x;
    int w = tid >> 6, lane = tid & 63;
    int r = lane & 15, quad = lane >> 4;

    {   // stage 64 rows x 256 bf16 (512 B = 32 uint4 per row); 4 threads/row x 8 uint4
        int row = tid >> 2, slot = tid & 3;
        const uint4* g = (const uint4*)(xb + (size_t)(row0 + row) * DIN);
        uint4* l = (uint4*)(As + row * LDSW);  // 560 B stride, 16B-aligned
        #pragma unroll
        for (int i = 0; i < 8; ++i)
            l[slot + 4 * i] = g[slot + 4 * i];
    }
    __syncthreads();

    #pragma unroll
    for (int ch = 0; ch < 2; ++ch) {           // col halves: 256 cols each
        f32x4 acc[4][4] = {};
        #pragma unroll
        for (int kc = 0; kc < 8; ++kc) {
            bf16x8 a[4], b[4];
            #pragma unroll
            for (int sub = 0; sub < 4; ++sub)
                a[sub] = *(const bf16x8*)(As + (sub * 16 + r) * LDSW + kc * 32 + quad * 8);
            #pragma unroll
            for (int t = 0; t < 4; ++t) {
                int col = ch * 256 + w * 64 + t * 16 + r;
                b[t] = *(const bf16x8*)(Wt + (size_t)col * DIN + kc * 32 + quad * 8);
            }
            #pragma unroll
            for (int t = 0; t < 4; ++t)
                #pragma unroll
                for (int sub = 0; sub < 4; ++sub)
                    acc[sub][t] = __builtin_amdgcn_mfma_f32_16x16x32_bf16(a[sub], b[t], acc[sub][t], 0, 0, 0);
        }
        #pragma unroll
        for (int sub = 0; sub < 4; ++sub) {
            #pragma unroll
            for (int j = 0; j < 4; ++j) {
                int row = row0 + sub * 16 + quad * 4 + j;
                if (row < NNODES) {
                    unsigned u = (unsigned)__builtin_amdgcn_cvt_pk_fp8_f32(
                                     acc[sub][0][j], acc[sub][1][j], 0, false);
                    u = (unsigned)__builtin_amdgcn_cvt_pk_fp8_f32(
                                     acc[sub][2][j], acc[sub][3][j], (int)u, true);
                    xp8[(size_t)row * 128 + ch * 64 + w * 16 + r] = u;
                }
            }
        }
    }
}

// a_s[n,h] = sum_c xp[n,h,c]*att_src[h,c], decoding the permuted fp8 layout.
// One wave per node; lane covers heads (lane>>3)*4+t, c = 2*(lane&7)+p.
__global__ void k_att(const unsigned* __restrict__ xp8,
                      const float* __restrict__ att_src,
                      const float* __restrict__ att_dst,
                      float* __restrict__ a_s, float* __restrict__ a_d) {
    __shared__ float sS[512], sD[512];
    int tid = threadIdx.x;
    sS[tid] = att_src[tid]; sS[tid + 256] = att_src[tid + 256];
    sD[tid] = att_dst[tid]; sD[tid + 256] = att_dst[tid + 256];
    __syncthreads();
    int nd = blockIdx.x * 4 + (tid >> 6);      // exactly 50000
    int ln = tid & 63;
    int m = ln & 7, g = ln >> 3;

    const uint2 q = *(const uint2*)(xp8 + (size_t)nd * 128 + ln * 2);
    f32x2 p0 = __builtin_amdgcn_cvt_pk_f32_fp8((int)q.x, false);
    f32x2 p1 = __builtin_amdgcn_cvt_pk_f32_fp8((int)q.x, true);
    f32x2 p2 = __builtin_amdgcn_cvt_pk_f32_fp8((int)q.y, false);
    f32x2 p3 = __builtin_amdgcn_cvt_pk_f32_fp8((int)q.y, true);
    float f[8] = {p0.x, p0.y, p1.x, p1.y, p2.x, p2.y, p3.x, p3.y};

    float ps[4], pd[4];
    #pragma unroll
    for (int t = 0; t < 4; ++t) {
        int h = g * 4 + t;
        int c0 = 2 * m, c1 = 2 * m + 1;
        ps[t] = f[t] * sS[h * 16 + c0] + f[4 + t] * sS[h * 16 + c1];
        pd[t] = f[t] * sD[h * 16 + c0] + f[4 + t] * sD[h * 16 + c1];
    }
    #pragma unroll
    for (int mask = 1; mask <= 4; mask <<= 1) {
        #pragma unroll
        for (int t = 0; t < 4; ++t) {
            ps[t] += __shfl_xor(ps[t], mask, 64);
            pd[t] += __shfl_xor(pd[t], mask, 64);
        }
    }
    if (m == 0) {
        #pragma unroll
        for (int t = 0; t < 4; ++t) {
            a_s[nd * HEADS + g * 4 + t] = ps[t];
            a_d[nd * HEADS + g * 4 + t] = pd[t];
        }
    }
}

// One wave per dst node; fp8 permuted-payload gather, fp32 softmax state.
__global__ void k_conv(const int* __restrict__ csr, const int* __restrict__ rs,
                       const int* __restrict__ deg,
                       const unsigned* __restrict__ xp8,
                       const float* __restrict__ a_s, const float* __restrict__ a_d,
                       const float* __restrict__ bias, float* __restrict__ out) {
    int nd = blockIdx.x * 4 + (threadIdx.x >> 6);      // exactly 50000
    int ln = threadIdx.x & 63;
    int h0 = ln & 31;                                  // score duty head
    int base = (ln >> 3) * 4;                          // payload heads base
    float adn = a_d[nd * HEADS + h0];
    int beg = __builtin_amdgcn_readfirstlane(rs[nd]);
    int cnt = __builtin_amdgcn_readfirstlane(deg[nd]);
    const uint2* xv = (const uint2*)xp8;               // 64 uint2 per row

    float denom = 0.f;
    float acc[8] = {0, 0, 0, 0, 0, 0, 0, 0};

    #define EDGE_BODY(AV, QV)                                              \
    {                                                                      \
        float tt = (AV) + adn;                                             \
        tt = tt > 0.f ? tt : 0.2f * tt;                                    \
        float e = __expf(tt);                                              \
        denom += e;                                                        \
        float es0 = __shfl(e, base + 0, 64);                               \
        float es1 = __shfl(e, base + 1, 64);                               \
        float es2 = __shfl(e, base + 2, 64);                               \
        float es3 = __shfl(e, base + 3, 64);                               \
        f32x2 p0 = __builtin_amdgcn_cvt_pk_f32_fp8((int)(QV).x, false);    \
        f32x2 p1 = __builtin_amdgcn_cvt_pk_f32_fp8((int)(QV).x, true);     \
        f32x2 p2 = __builtin_amdgcn_cvt_pk_f32_fp8((int)(QV).y, false);    \
        f32x2 p3 = __builtin_amdgcn_cvt_pk_f32_fp8((int)(QV).y, true);     \
        acc[0] += es0 * p0.x; acc[1] += es1 * p0.y;                        \
        acc[2] += es2 * p1.x; acc[3] += es3 * p1.y;                        \
        acc[4] += es0 * p2.x; acc[5] += es1 * p2.y;                        \
        acc[6] += es2 * p3.x; acc[7] += es3 * p3.y;                        \
    }

    {   // self contribution
        float av = a_s[nd * HEADS + h0];
        uint2 qv = xv[(size_t)nd * 64 + ln];
        EDGE_BODY(av, qv)
    }

    int i = 0;
    for (; i + 8 <= cnt; i += 8) {
        int sv[8];
        #pragma unroll
        for (int k = 0; k < 8; ++k) sv[k] = csr[beg + i + k];
        float av[8];
        #pragma unroll
        for (int k = 0; k < 8; ++k) av[k] = a_s[sv[k] * HEADS + h0];
        uint2 qv[8];
        #pragma unroll
        for (int k = 0; k < 8; ++k) qv[k] = xv[(size_t)sv[k] * 64 + ln];
        #pragma unroll
        for (int k = 0; k < 8; ++k) EDGE_BODY(av[k], qv[k])
    }
    for (; i < cnt; ++i) {
        int s = csr[beg + i];
        float av = a_s[s * HEADS + h0];
        uint2 qv = xv[(size_t)s * 64 + ln];
        EDGE_BODY(av, qv)
    }
    #undef EDGE_BODY

    float inv = 1.f / (denom + 1e-16f);
    float iv0 = __shfl(inv, base + 0, 64);
    float iv1 = __shfl(inv, base + 1, 64);
    float iv2 = __shfl(inv, base + 2, 64);
    float iv3 = __shfl(inv, base + 3, 64);
    acc[0] *= iv0; acc[1] *= iv1; acc[2] *= iv2; acc[3] *= iv3;
    acc[4] *= iv0; acc[5] *= iv1; acc[6] *= iv2; acc[7] *= iv3;

    #pragma unroll
    for (int mask = 8; mask <= 32; mask <<= 1) {
        #pragma unroll
        for (int j = 0; j < 8; ++j) acc[j] += __shfl_xor(acc[j], mask, 64);
    }
    if (ln < 8) {
        #pragma unroll
        for (int p = 0; p < 2; ++p) {
            int c = 2 * ln + p;
            float o = (acc[p * 4] + acc[p * 4 + 1] + acc[p * 4 + 2] + acc[p * 4 + 3])
                      * (1.0f / HEADS) + bias[c];
            out[(size_t)nd * CDIM + c] = o > 0.f ? o : expm1f(o);
        }
    }
}

// x1 = elu(xb @ w1t + b1); wave = 64 rows x 64 cols; 782 active waves
__global__ void k_mlp1(const unsigned short* __restrict__ xb,
                       const unsigned short* __restrict__ w1t,
                       const float* __restrict__ bb1, unsigned short* __restrict__ x1) {
    int wave = blockIdx.x * 4 + (threadIdx.x >> 6);
    if (wave >= 782) return;
    int lane = threadIdx.x & 63;
    int r = lane & 15, quad = lane >> 4;
    int row0 = wave * 64;

    f32x4 acc[4][4] = {};
    #pragma unroll
    for (int kc = 0; kc < 8; ++kc) {
        bf16x8 a[4];
        #pragma unroll
        for (int sub = 0; sub < 4; ++sub) {
            int row = row0 + sub * 16 + r;
            if (row0 + sub * 16 < NNODES)
                a[sub] = *(const bf16x8*)(xb + (size_t)row * DIN + kc * 32 + quad * 8);
            else {
                union { unsigned short u[8]; bf16x8 v; } z;
                #pragma unroll
                for (int j = 0; j < 8; ++j) z.u[j] = 0;
                a[sub] = z.v;
            }
        }
        #pragma unroll
        for (int t = 0; t < 4; ++t) {
            int col = t * 16 + r;
            bf16x8 b = *(const bf16x8*)(w1t + (size_t)col * DIN + kc * 32 + quad * 8);
            #pragma unroll
            for (int sub = 0; sub < 4; ++sub)
                acc[sub][t] = __builtin_amdgcn_mfma_f32_16x16x32_bf16(a[sub], b, acc[sub][t], 0, 0, 0);
        }
    }
    #pragma unroll
    for (int sub = 0; sub < 4; ++sub) {
        #pragma unroll
        for (int t = 0; t < 4; ++t) {
            int col = t * 16 + r;
            float bv = bb1[col];
            #pragma unroll
            for (int j = 0; j < 4; ++j) {
                int row = row0 + sub * 16 + quad * 4 + j;
                if (row < NNODES) {
                    float v = acc[sub][t][j] + bv;
                    v = v > 0.f ? v : expm1f(v);
                    x1[(size_t)row * 64 + col] = f2b(v);
                }
            }
        }
    }
}

// out = elu(x1 @ w2t + b2); wave = 16 rows x 16 cols; 3125 active waves
__global__ void k_mlp2(const unsigned short* __restrict__ x1,
                       const unsigned short* __restrict__ w2t,
                       const float* __restrict__ bb2, float* __restrict__ out) {
    int wave = blockIdx.x * 4 + (threadIdx.x >> 6);
    if (wave >= 3125) return;
    int lane = threadIdx.x & 63;
    int r = lane & 15, quad = lane >> 4;

    f32x4 acc = {};
    #pragma unroll
    for (int kc = 0; kc < 2; ++kc) {
        bf16x8 a = *(const bf16x8*)(x1 + (size_t)(wave * 16 + r) * 64 + kc * 32 + quad * 8);
        bf16x8 b = *(const bf16x8*)(w2t + (size_t)r * 64 + kc * 32 + quad * 8);
        acc = __builtin_amdgcn_mfma_f32_16x16x32_bf16(a, b, acc, 0, 0, 0);
    }
    float bv = bb2[r];
    #pragma unroll
    for (int j = 0; j < 4; ++j) {
        int row = wave * 16 + quad * 4 + j;
        float v = acc[j] + bv;
        v = v > 0.f ? v : expm1f(v);
        out[(size_t)row * CDIM + r] = v;
    }
}

extern "C" void kernel_launch(void* const* d_in, const int* in_sizes, int n_in,
                              void* d_out, int out_size, void* d_ws, size_t ws_size,
                              hipStream_t stream) {
    const float* x  = (const float*)d_in[0];
    const int* ei   = (const int*)d_in[1];
    const float* W[2]    = {(const float*)d_in[2], (const float*)d_in[6]};
    const float* atS[2]  = {(const float*)d_in[3], (const float*)d_in[7]};
    const float* atD[2]  = {(const float*)d_in[4], (const float*)d_in[8]};
    const float* bias[2] = {(const float*)d_in[5], (const float*)d_in[9]};
    const float* w1 = (const float*)d_in[10];
    const float* b1 = (const float*)d_in[11];
    const float* w2 = (const float*)d_in[12];
    const float* b2 = (const float*)d_in[13];
    float* out = (float*)d_out;

    char* ws = (char*)d_ws;
    unsigned* xp8 = (unsigned*)(ws);                          // 25,600,000 B
    unsigned short* xb  = (unsigned short*)(ws + 25600000);   // 25,600,000 B
    unsigned short* Wt  = (unsigned short*)(ws + 51200000);   //    262,144 B (xb tail-read spills here: benign bf16)
    unsigned short* w1t = (unsigned short*)(ws + 51462144);   //     32,768 B
    unsigned short* w2t = (unsigned short*)(ws + 51494912);   //      2,048 B
    float* a_s = (float*)(ws + 51496960);                     //  6,400,000 B
    float* a_d = (float*)(ws + 57896960);                     //  6,400,000 B
    unsigned short* x1 = (unsigned short*)(ws + 51496960);    // alias a_s (dead before mlp1)
    int* deg   = (int*)(ws + 64296960);                       //    200,000 B
    int* rs    = (int*)(ws + 64496960);                       //    200,000 B
    int* cur   = (int*)(ws + 64696960);                       //    200,000 B
    int* part  = (int*)(ws + 64896960);                       //    200,000 B
    int* bsum  = (int*)(ws + 65096960);                       //      1,024 B
    int* csr   = (int*)(ws + 65097984);                       //  3,200,000 B
    int* flag  = (int*)(ws + 68297984);                       //          4 B

    k_detect<<<1, 64, 0, stream>>>(ei, flag);
    k_zero_deg<<<SCAN_B, 256, 0, stream>>>(deg);
    k_hist    <<<3125, 256, 0, stream>>>(ei, flag, deg);
    k_scan_blk<<<SCAN_B, 256, 0, stream>>>(deg, part, bsum);
    k_scan_top<<<1, 256, 0, stream>>>(bsum);
    k_scan_add<<<SCAN_B, 256, 0, stream>>>(part, bsum, rs, cur);
    k_scatter <<<3125, 256, 0, stream>>>(ei, flag, cur, csr);

    k_cast_x<<<12500, 256, 0, stream>>>(x, xb);
    k_tr<<<64, 256, 0, stream>>>(w1, w1t, DIN, 64);
    k_tr<<<16, 64, 0, stream>>>(w2, w2t, 64, CDIM);

    for (int cv = 0; cv < 2; ++cv) {
        k_tr     <<<512, 256, 0, stream>>>(W[cv], Wt, DIN, NH);
        k_gemm_xp<<<782, 256, 0, stream>>>(xb, Wt, xp8);
        k_att    <<<12500, 256, 0, stream>>>(xp8, atS[cv], atD[cv], a_s, a_d);
        k_conv   <<<12500, 256, 0, stream>>>(csr, rs, deg, xp8, a_s, a_d,
                                             bias[cv], out + (size_t)cv * 800000);
    }
    k_mlp1<<<196, 256, 0, stream>>>(xb, w1t, b1, x1);
    k_mlp2<<<782, 256, 0, stream>>>(x1, w2t, b2, out + 1600000);
}